// Round 22
// baseline (227.440 us; speedup 1.0000x reference)
//
#include <hip/hip_runtime.h>
#include <hip/hip_bf16.h>

#define LJ 256008       // T*BANDS
#define TN 32001
#define OUT_LEN 32000

typedef __attribute__((ext_vector_type(8))) short short8v;
typedef __attribute__((ext_vector_type(8))) __bf16 bf16x8;
typedef __attribute__((ext_vector_type(4))) float f32x4;

__device__ __forceinline__ unsigned short f2bu(float f) {
    union { __hip_bfloat16 h; unsigned short u; } cv; cv.h = __float2bfloat16(f); return cv.u;
}
__device__ __forceinline__ uint4 pack8(const unsigned short* h) {
    return make_uint4((unsigned)h[0] | ((unsigned)h[1] << 16),
                      (unsigned)h[2] | ((unsigned)h[3] << 16),
                      (unsigned)h[4] | ((unsigned)h[5] << 16),
                      (unsigned)h[6] | ((unsigned)h[7] << 16));
}
__device__ __forceinline__ f32x4 mfma16(uint4 a, uint4 b, f32x4 c) {
    union { uint4 u; short8v s; bf16x8 v; } ua, ub;
    ua.u = a; ub.u = b;
    return __builtin_amdgcn_mfma_f32_16x16x32_bf16(ua.v, ub.v, c, 0, 0, 0);
}

// ---------------- h1 = relu(x @ lstm_W1 + b1), stored [i][b] (f32) ----------------
__global__ __launch_bounds__(256) void k_h1(const float* __restrict__ x,
                                            const float* __restrict__ W1,
                                            const float* __restrict__ b1,
                                            float* __restrict__ h1)
{
    int idx = blockIdx.x * 256 + threadIdx.x;   // 4096 outputs
    if (idx >= 4096) return;
    int b = idx >> 6, i = idx & 63;
    float acc = b1[i];
    #pragma unroll
    for (int f = 0; f < 16; ++f)
        acc += x[b * 16 + f] * W1[f * 64 + i];
    h1[i * 64 + b] = fmaxf(acc, 0.f);
}

// ---- MFMA GEMM (pure): stage W2 chunk -> LDS, MFMA, store edc.  LDS 40KB -> 4 blocks/CU -------
__global__ __launch_bounds__(512) void k_gemm(const float* __restrict__ W2,
                                              const float* __restrict__ b2,
                                              const float* __restrict__ h1,
                                              float* __restrict__ edc)
{
    __shared__ float w2f[8192];                            // 32 KB: [row(32)][col(256)]
    __shared__ __align__(16) unsigned short afr[4096];     // 8 KB: [bt(4)][kb(2)][lane][e]
    int tid = threadIdx.x;
    long C0 = (long)blockIdx.x * 256;
    float4 z4 = make_float4(0.f, 0.f, 0.f, 0.f);

    // stage A fragments (block-invariant, one slot per thread)
    {
        int bt = tid >> 7, kb = (tid >> 6) & 1, l = tid & 63;
        int q = l >> 4, r = l & 15;
        unsigned short hh[8];
        #pragma unroll
        for (int e = 0; e < 8; ++e)
            hh[e] = f2bu(h1[(32 * kb + 8 * q + e) * 64 + 16 * bt + r]);
        *(uint4*)(&afr[tid * 8]) = pack8(hh);
    }
    // stage w2f chunk kb=0 (rows 0..31), coalesced float4
    #pragma unroll
    for (int s = 0; s < 4; ++s) {
        int slot = tid + 512 * s;
        int row = slot >> 6, c4 = slot & 63;
        long col = C0 + 4 * c4;
        float4 v = (col < LJ) ? *(const float4*)(W2 + (long)row * LJ + col) : z4;
        *(float4*)(&w2f[row * 256 + 4 * c4]) = v;
    }
    __syncthreads();

    int lane = tid & 63, wv = tid >> 6;
    int q = lane >> 4, r = lane & 15;
    f32x4 acc[2][4];
    #pragma unroll
    for (int c = 0; c < 2; ++c)
        #pragma unroll
        for (int b = 0; b < 4; ++b) acc[c][b] = (f32x4){0.f, 0.f, 0.f, 0.f};

    // MFMA kb=0
    #pragma unroll
    for (int ctl = 0; ctl < 2; ++ctl) {
        int ct = wv * 2 + ctl;
        unsigned short hh[8];
        #pragma unroll
        for (int e = 0; e < 8; ++e)
            hh[e] = f2bu(w2f[(8 * q + e) * 256 + 16 * ct + r]);
        uint4 braw = pack8(hh);
        #pragma unroll
        for (int bt = 0; bt < 4; ++bt) {
            uint4 araw = *(const uint4*)(&afr[((bt * 2 + 0) * 64 + lane) * 8]);
            acc[ctl][bt] = mfma16(araw, braw, acc[ctl][bt]);
        }
    }
    __syncthreads();
    // stage w2f chunk kb=1 (rows 32..63)
    #pragma unroll
    for (int s = 0; s < 4; ++s) {
        int slot = tid + 512 * s;
        int row = slot >> 6, c4 = slot & 63;
        long col = C0 + 4 * c4;
        float4 v = (col < LJ) ? *(const float4*)(W2 + (long)(32 + row) * LJ + col) : z4;
        *(float4*)(&w2f[row * 256 + 4 * c4]) = v;
    }
    __syncthreads();
    // MFMA kb=1
    #pragma unroll
    for (int ctl = 0; ctl < 2; ++ctl) {
        int ct = wv * 2 + ctl;
        unsigned short hh[8];
        #pragma unroll
        for (int e = 0; e < 8; ++e)
            hh[e] = f2bu(w2f[(8 * q + e) * 256 + 16 * ct + r]);
        uint4 braw = pack8(hh);
        #pragma unroll
        for (int bt = 0; bt < 4; ++bt) {
            uint4 araw = *(const uint4*)(&afr[((bt * 2 + 1) * 64 + lane) * 8]);
            acc[ctl][bt] = mfma16(araw, braw, acc[ctl][bt]);
        }
    }

    // epilogue: edc stores only
    #pragma unroll
    for (int ctl = 0; ctl < 2; ++ctl) {
        int ct = wv * 2 + ctl;
        long col = C0 + 16 * ct + r;
        if (col < LJ) {
            float bias = b2[col];
            #pragma unroll
            for (int bt = 0; bt < 4; ++bt)
                #pragma unroll
                for (int rg = 0; rg < 4; ++rg)
                    edc[(long)(16 * bt + 4 * q + rg) * LJ + col] = acc[ctl][bt][rg] + bias;
        }
    }
}

// ---- exact-f32 edc1d + per-block band col-sums (W2 re-read hits L3) ---------------------------
__global__ __launch_bounds__(256) void k_e1d(const float* __restrict__ W2,
                                             const float* __restrict__ b2,
                                             const float* __restrict__ h1,
                                             float* __restrict__ edc1d,
                                             float* __restrict__ wbP)
{
    __shared__ float h1T[64 * 68];                 // 17.4 KB [b][i]
    __shared__ float wbndT[32 * 68];               // 8.7 KB  [tl][i]
    int tid = threadIdx.x;
    long C0 = (long)blockIdx.x * 256;

    // stage h1 transposed
    #pragma unroll
    for (int s = 0; s < 16; ++s) {
        int g = tid + 256 * s;
        h1T[(g & 63) * 68 + (g >> 6)] = h1[g];
    }
    // band sums: each (i, tl) reads its 8 cols of W2 (L3-hot), makes wbndT + wbP
    #pragma unroll
    for (int s = 0; s < 8; ++s) {
        int e = tid + 256 * s;                     // 2048 entries
        int i = e >> 5, tl = e & 31;
        long c8 = C0 + 8 * tl;
        float v0 = 0.f, v1 = 0.f, v2 = 0.f, v3 = 0.f, v4 = 0.f, v5 = 0.f, v6 = 0.f, v7 = 0.f;
        if (c8 + 7 < LJ) {
            float4 u0 = *(const float4*)(W2 + (long)i * LJ + c8);
            float4 u1 = *(const float4*)(W2 + (long)i * LJ + c8 + 4);
            v0 = u0.x; v1 = u0.y; v2 = u0.z; v3 = u0.w;
            v4 = u1.x; v5 = u1.y; v6 = u1.z; v7 = u1.w;
        }
        wbndT[tl * 68 + i] = ((v0 + v1) + (v2 + v3)) + ((v4 + v5) + (v6 + v7));
        // per-band reduce over the 32-thread tl-group (half-wave shfl)
        float bv[8] = {v0, v1, v2, v3, v4, v5, v6, v7};
        #pragma unroll
        for (int m = 1; m < 32; m <<= 1)
            #pragma unroll
            for (int bd = 0; bd < 8; ++bd)
                bv[bd] += __shfl_xor(bv[bd], m);
        if (tl == 0) {
            #pragma unroll
            for (int bd = 0; bd < 8; ++bd)
                wbP[(long)blockIdx.x * 512 + i * 8 + bd] = bv[bd];
        }
    }
    __syncthreads();

    // dot: thread owns column tl, batches b0 + 8k
    int tl = tid & 31;
    int b0 = tid >> 5;                             // 0..7
    long c8 = C0 + 8 * tl;
    if (c8 + 7 < LJ) {
        float4 bb0 = *(const float4*)(b2 + c8);
        float4 bb1 = *(const float4*)(b2 + c8 + 4);
        float bias = ((bb0.x + bb0.y) + (bb0.z + bb0.w)) + ((bb1.x + bb1.y) + (bb1.z + bb1.w));
        float d[8];
        #pragma unroll
        for (int k = 0; k < 8; ++k) d[k] = bias;
        #pragma unroll
        for (int i0 = 0; i0 < 64; i0 += 4) {
            float4 wA = *(const float4*)(&wbndT[tl * 68 + i0]);
            #pragma unroll
            for (int k = 0; k < 8; ++k) {
                float4 hA = *(const float4*)(&h1T[(b0 + 8 * k) * 68 + i0]);
                d[k] += hA.x * wA.x + hA.y * wA.y + hA.z * wA.z + hA.w * wA.w;
            }
        }
        int tcol = (int)(C0 >> 3) + tl;
        #pragma unroll
        for (int k = 0; k < 8; ++k)
            edc1d[(long)(b0 + 8 * k) * TN + tcol] = d[k] * 0.125f;
    }
}

// ---- reduce wbP over blocks + b2 band sums -> sums[b][band][{all,q1,q4}] ----------------------
__global__ __launch_bounds__(512) void k_sums(const float* __restrict__ wbP,
                                              const float* __restrict__ b2,
                                              const float* __restrict__ h1,
                                              float* __restrict__ sums)
{
    __shared__ float wbL[512], wbL1[512], wbL4[512];   // [i*8+band] all/q1/q4
    __shared__ float bsum[24];                          // [band*3+cls]
    int tid = threadIdx.x;
    // (a) reduce wbP over 1001 blocks
    {
        float all = 0.f, q1 = 0.f, q4 = 0.f;
        for (int blk = 0; blk < 1001; ++blk) {
            float v = wbP[(long)blk * 512 + tid];
            all += v;
            if (blk < 250) q1 += v;
            if (blk >= 750) q4 += v;
        }
        wbL[tid] = all; wbL1[tid] = q1; wbL4[tid] = q4;
    }
    // (b) b2 band-class sums
    if (tid < 24) bsum[tid] = 0.f;
    __syncthreads();
    {
        float a[8] = {0,0,0,0,0,0,0,0}, s1[8] = {0,0,0,0,0,0,0,0}, s4[8] = {0,0,0,0,0,0,0,0};
        for (int t = tid; t <= 32000; t += 512) {
            float4 u0 = *(const float4*)(b2 + 8 * t);
            float4 u1 = *(const float4*)(b2 + 8 * t + 4);
            float vv[8] = {u0.x, u0.y, u0.z, u0.w, u1.x, u1.y, u1.z, u1.w};
            #pragma unroll
            for (int bd = 0; bd < 8; ++bd) {
                a[bd] += vv[bd];
                if (t < 8000) s1[bd] += vv[bd];
                if (t >= 24000) s4[bd] += vv[bd];
            }
        }
        #pragma unroll
        for (int bd = 0; bd < 8; ++bd) {
            atomicAdd(&bsum[bd * 3 + 0], a[bd]);
            atomicAdd(&bsum[bd * 3 + 1], s1[bd]);
            atomicAdd(&bsum[bd * 3 + 2], s4[bd]);
        }
    }
    __syncthreads();
    // (c) sums[b][band][cls] = bsum + sum_i h1[b][i] * wbX[i][band]
    {
        int b = tid >> 3, band = tid & 7;
        float accA = bsum[band * 3 + 0];
        float acc1 = bsum[band * 3 + 1];
        float acc4 = bsum[band * 3 + 2];
        for (int i = 0; i < 64; ++i) {
            float h = h1[i * 64 + b];
            accA += h * wbL[i * 8 + band];
            acc1 += h * wbL1[i * 8 + band];
            acc4 += h * wbL4[i * 8 + band];
        }
        sums[b * 24 + band * 3 + 0] = accA;
        sums[b * 24 + band * 3 + 1] = acc1;
        sums[b * 24 + band * 3 + 2] = acc4;
    }
}

// ---------------- small MLP head: one block per batch row, f32 outputs ----------------
__global__ __launch_bounds__(64) void k_mlp(const float* __restrict__ x,
    const float* __restrict__ sums,
    const float* __restrict__ eW1, const float* __restrict__ eb1,
    const float* __restrict__ eW2, const float* __restrict__ eb2,
    const float* __restrict__ dW1, const float* __restrict__ db1,
    const float* __restrict__ dW2, const float* __restrict__ db2,
    const float* __restrict__ aW1, const float* __restrict__ ab1,
    const float* __restrict__ aW2, const float* __restrict__ ab2,
    const float* __restrict__ bW1, const float* __restrict__ bb1,
    const float* __restrict__ bW2, const float* __restrict__ bb2,
    float* __restrict__ out_lk, float* __restrict__ out_a, float* __restrict__ out_b)
{
    int b = blockIdx.x, o = threadIdx.x;
    __shared__ float feat[16], a1[64], hh[64], t1[64];
    if (o < 16) {
        float v;
        if (o < 8) v = sums[b * 24 + o * 3] * (1.f / 32001.f);
        else {
            int band = o - 8;
            v = sums[b * 24 + band * 3 + 2] * (1.f / 8001.f)
              - sums[b * 24 + band * 3 + 1] * (1.f / 8000.f);
        }
        feat[o] = v;
    }
    __syncthreads();
    {   float acc = eb1[o];
        #pragma unroll
        for (int c = 0; c < 16; ++c) acc += feat[c] * eW1[c * 64 + o];
        a1[o] = fmaxf(acc, 0.f); }
    __syncthreads();
    {   float acc = eb2[o];
        for (int c = 0; c < 64; ++c) acc += a1[c] * eW2[c * 64 + o];
        hh[o] = fmaxf(acc, 0.f); }
    __syncthreads();
    {   float acc = db1[o];
        #pragma unroll
        for (int c = 0; c < 3; ++c) acc += x[b * 16 + c] * dW1[c * 64 + o];
        for (int c = 0; c < 64; ++c) acc += hh[c] * dW1[(3 + c) * 64 + o];
        t1[o] = fmaxf(acc, 0.f); }
    __syncthreads();
    if (o < 16) {
        float acc = db2[o];
        for (int c = 0; c < 64; ++c) acc += t1[c] * dW2[c * 16 + o];
        out_lk[b * 16 + o] = acc;
    }
    __syncthreads();
    if (o < 32) {
        float acc = ab1[o];
        for (int c = 0; c < 64; ++c) acc += hh[c] * aW1[c * 32 + o];
        t1[o] = fmaxf(acc, 0.f);
    }
    __syncthreads();
    if (o < 16) {
        float acc = ab2[o];
        for (int c = 0; c < 32; ++c) acc += t1[c] * aW2[c * 16 + o];
        out_a[b * 16 + o] = acc;
    }
    __syncthreads();
    if (o < 32) {
        float acc = bb1[o];
        for (int c = 0; c < 64; ++c) acc += hh[c] * bW1[c * 32 + o];
        t1[o] = fmaxf(acc, 0.f);
    }
    __syncthreads();
    if (o < 16) {
        float acc = bb2[o];
        for (int c = 0; c < 32; ++c) acc += t1[c] * bW2[c * 16 + o];
        out_b[b * 16 + o] = acc;
    }
}

// ---------------- parity stage 1: packed bits (per-(b, 256-chunk) inclusive XOR scan) ----------
__global__ __launch_bounds__(256) void k_par1(const int* __restrict__ flips,
                                              unsigned* __restrict__ parbits,
                                              unsigned* __restrict__ ctot)
{
    int b = blockIdx.x, c = blockIdx.y, tid = threadIdx.x;
    int t = c * 256 + tid;
    int bit = (t == 0) ? 0 : (flips[(long)b * OUT_LEN + t] & 1);
    int lane = tid & 63, wv = tid >> 6;
    unsigned long long mask = __ballot(bit != 0);
    int below = ((int)__popcll(mask & ((1ull << lane) - 1ull))) & 1;
    int incl = below ^ bit;
    __shared__ int wtot[4];
    if (lane == 0) wtot[wv] = ((int)__popcll(mask)) & 1;
    __syncthreads();
    int pre = 0;
    for (int w = 0; w < wv; ++w) pre ^= wtot[w];
    int inclB = pre ^ incl;
    unsigned long long m2 = __ballot(inclB != 0);
    if (lane == 0)  parbits[b * 1000 + c * 8 + wv * 2 + 0] = (unsigned)(m2 & 0xffffffffull);
    if (lane == 32) parbits[b * 1000 + c * 8 + wv * 2 + 1] = (unsigned)(m2 >> 32);
    if (tid == 0) ctot[c * 64 + b] = (unsigned)(wtot[0] ^ wtot[1] ^ wtot[2] ^ wtot[3]);
}

// ---------------- parity stage 2: exclusive prefix over chunks ----------------
__global__ __launch_bounds__(64) void k_par2(const unsigned* __restrict__ ctot,
                                             unsigned* __restrict__ cpref)
{
    int b = threadIdx.x;
    unsigned carry = 0;
    for (int c = 0; c < 125; ++c) {
        cpref[c * 64 + b] = carry;
        carry ^= ctot[c * 64 + b];
    }
}

// ------- MFMA Toeplitz conv (late+early) + amp + sign -> rir ----------------------------------
__global__ __launch_bounds__(512) void k_convm(const float* __restrict__ edc1d,
    const float* __restrict__ lk, const float* __restrict__ eg,
    const unsigned* __restrict__ parbits, const unsigned* __restrict__ cpref,
    float* __restrict__ rir)
{
    __shared__ float kerf[1024];
    __shared__ __align__(16) unsigned short afr[33 * 64 * 8];  // A frags [kb][lane][e]
    __shared__ __align__(16) unsigned short sbf[3136];         // swizzled bf16 window
    __shared__ float sf32[2049];
    int b = blockIdx.x, tb0 = blockIdx.y * 2048, tid = threadIdx.x;
    const float* src = edc1d + (long)b * TN;
    for (int k = tid; k < 1024; k += 512)
        kerf[k] = lk[k] + (k < 43 ? eg[k] : 0.f);
    for (int ch = tid; ch < 388; ch += 512) {
        unsigned short h[8];
        #pragma unroll
        for (int e = 0; e < 8; ++e) {
            int gt = tb0 + ch * 8 + e - 1031;
            float v = (gt >= 0 && gt <= OUT_LEN) ? src[gt] : 0.f;
            h[e] = f2bu(v);
        }
        int cs = ch ^ ((ch >> 3) & 7);
        *(uint4*)(&sbf[cs * 8]) = pack8(h);
    }
    for (int u = tid; u < 2049; u += 512) {
        int gt = tb0 + u;
        sf32[u] = (gt <= OUT_LEN) ? src[gt] : 0.f;
    }
    __syncthreads();
    for (int sl = tid; sl < 33 * 64; sl += 512) {
        int kb = sl >> 6, l = sl & 63;
        int x0 = kb * 32 - 1 + (l & 15) - 8 * (l >> 4);    // x = x0 - e
        unsigned short h[8];
        #pragma unroll
        for (int e = 0; e < 8; ++e) {
            int x = x0 - e;
            float v = (x >= 0 && x < 1024) ? kerf[x] : 0.f;
            h[e] = f2bu(v);
        }
        *(uint4*)(&afr[sl * 8]) = pack8(h);
    }
    __syncthreads();
    int lane = tid & 63, wv = tid >> 6;                    // 8 waves, 1 C-tile each
    int tb = tb0 + wv * 256;
    int cq = wv * 256 + 16 * (lane & 15) + 8 * (lane >> 4) + 1032;  // B chunk base (kb=0)
    f32x4 acc = {0.f, 0.f, 0.f, 0.f};
    for (int kb = 0; kb < 33; ++kb) {
        uint4 araw = *(const uint4*)(&afr[(kb * 64 + lane) * 8]);
        int ch = (cq - (kb << 5)) >> 3;
        int cs = ch ^ ((ch >> 3) & 7);
        uint4 braw = *(const uint4*)(&sbf[cs * 8]);
        acc = mfma16(araw, braw, acc);
    }
    int c = lane & 15, q = lane >> 4;
    int t4 = tb + 16 * c + 4 * q;
    if (t4 < OUT_LEN) {
        int u0 = t4 - tb0;
        unsigned pw = parbits[b * 1000 + (t4 >> 5)];       // 4 bits same word (t4%4==0)
        unsigned cp = cpref[(t4 >> 8) * 64 + b] & 1u;
        int sh = t4 & 31;
        float sv[5];
        #pragma unroll
        for (int e = 0; e < 5; ++e) sv[e] = sf32[u0 + e];
        float r[4];
        #pragma unroll
        for (int reg = 0; reg < 4; ++reg) {
            float diff = sv[reg] - sv[reg + 1];
            float amp = diff > 0.f ? sqrtf(diff) : 0.f;
            unsigned p = ((pw >> (sh + reg)) & 1u) ^ cp;
            r[reg] = acc[reg] * amp * (p ? -1.f : 1.f);
        }
        *(float4*)(rir + (long)b * OUT_LEN + t4) = make_float4(r[0], r[1], r[2], r[3]);
    }
}

extern "C" void kernel_launch(void* const* d_in, const int* in_sizes, int n_in,
                              void* d_out, int out_size, void* d_ws, size_t ws_size,
                              hipStream_t stream) {
    (void)in_sizes; (void)n_in; (void)out_size; (void)ws_size;
    const float* x    = (const float*)d_in[0];
    const float* lW1  = (const float*)d_in[1];  const float* lb1 = (const float*)d_in[2];
    const float* lW2  = (const float*)d_in[3];  const float* lb2 = (const float*)d_in[4];
    const float* eW1  = (const float*)d_in[5];  const float* eb1 = (const float*)d_in[6];
    const float* eW2  = (const float*)d_in[7];  const float* eb2 = (const float*)d_in[8];
    const float* dW1  = (const float*)d_in[9];  const float* db1 = (const float*)d_in[10];
    const float* dW2  = (const float*)d_in[11]; const float* db2 = (const float*)d_in[12];
    const float* aW1  = (const float*)d_in[13]; const float* ab1 = (const float*)d_in[14];
    const float* aW2  = (const float*)d_in[15]; const float* ab2 = (const float*)d_in[16];
    const float* bW1  = (const float*)d_in[17]; const float* bb1 = (const float*)d_in[18];
    const float* bW2  = (const float*)d_in[19]; const float* bb2 = (const float*)d_in[20];
    const float* eg   = (const float*)d_in[21]; const float* lkk = (const float*)d_in[22];
    const int* flips  = (const int*)d_in[23];

    float* out = (float*)d_out;                    // f32 output buffer
    float* rir = out;                              // 2,048,000
    float* edc = out + 2048000;                    // 16,384,512
    float* olk = out + 18432512;                   // 1,024
    float* oa  = out + 18433536;                   // 1,024
    float* ob  = out + 18434560;                   // 1,024

    // -------- ws layout (<= 10.6 MB, well under proven 18.65 MB) --------
    char* wsb = (char*)d_ws;
    float*    ws_h1   = (float*)(wsb + 1024);       // 16,384 B
    unsigned* ws_ct   = (unsigned*)(wsb + 18432);   // 32,000 B
    unsigned* ws_cp   = (unsigned*)(wsb + 50688);   // 32,000 B
    unsigned* ws_pb   = (unsigned*)(wsb + 82944);   // 256,000 B
    float*    ws_sums = (float*)(wsb + 339200);     // 6,144 B
    float*    ws_e1d  = (float*)(wsb + 346112);     // 8,192,256 B -> ends 8,538,368
    float*    ws_wbp  = (float*)(wsb + 8538368);    // 1001*512*4 = 2,050,048 B -> 10,588,416

    k_h1<<<16, 256, 0, stream>>>(x, lW1, lb1, ws_h1);
    k_par1<<<dim3(64, 125), 256, 0, stream>>>(flips, ws_pb, ws_ct);
    k_par2<<<1, 64, 0, stream>>>(ws_ct, ws_cp);
    k_gemm<<<1001, 512, 0, stream>>>(lW2, lb2, ws_h1, edc);
    k_e1d<<<1001, 256, 0, stream>>>(lW2, lb2, ws_h1, ws_e1d, ws_wbp);
    k_sums<<<1, 512, 0, stream>>>(ws_wbp, lb2, ws_h1, ws_sums);
    k_mlp<<<64, 64, 0, stream>>>(x, ws_sums, eW1, eb1, eW2, eb2, dW1, db1, dW2, db2,
                                 aW1, ab1, aW2, ab2, bW1, bb1, bW2, bb2, olk, oa, ob);
    k_convm<<<dim3(64, 16), 512, 0, stream>>>(ws_e1d, lkk, eg, ws_pb, ws_cp, rir);
}

// Round 23
// 181.069 us; speedup vs baseline: 1.2561x; 1.2561x over previous
//
#include <hip/hip_runtime.h>
#include <hip/hip_bf16.h>

#define LJ 256008       // T*BANDS
#define TN 32001
#define OUT_LEN 32000

typedef __attribute__((ext_vector_type(8))) short short8v;
typedef __attribute__((ext_vector_type(8))) __bf16 bf16x8;
typedef __attribute__((ext_vector_type(4))) float f32x4;

__device__ __forceinline__ unsigned short f2bu(float f) {
    union { __hip_bfloat16 h; unsigned short u; } cv; cv.h = __float2bfloat16(f); return cv.u;
}
__device__ __forceinline__ uint4 pack8(const unsigned short* h) {
    return make_uint4((unsigned)h[0] | ((unsigned)h[1] << 16),
                      (unsigned)h[2] | ((unsigned)h[3] << 16),
                      (unsigned)h[4] | ((unsigned)h[5] << 16),
                      (unsigned)h[6] | ((unsigned)h[7] << 16));
}
__device__ __forceinline__ f32x4 mfma16(uint4 a, uint4 b, f32x4 c) {
    union { uint4 u; short8v s; bf16x8 v; } ua, ub;
    ua.u = a; ub.u = b;
    return __builtin_amdgcn_mfma_f32_16x16x32_bf16(ua.v, ub.v, c, 0, 0, 0);
}

// ---------------- h1 = relu(x @ lstm_W1 + b1), stored [i][b] (f32) ----------------
__global__ __launch_bounds__(256) void k_h1(const float* __restrict__ x,
                                            const float* __restrict__ W1,
                                            const float* __restrict__ b1,
                                            float* __restrict__ h1)
{
    int idx = blockIdx.x * 256 + threadIdx.x;   // 4096 outputs
    if (idx >= 4096) return;
    int b = idx >> 6, i = idx & 63;
    float acc = b1[i];
    #pragma unroll
    for (int f = 0; f < 16; ++f)
        acc += x[b * 16 + f] * W1[f * 64 + i];
    h1[i * 64 + b] = fmaxf(acc, 0.f);
}

// ---- MFMA GEMM (pure): stage W2 chunk -> LDS, MFMA, store edc.  LDS 40KB -> 4 blocks/CU -------
__global__ __launch_bounds__(512) void k_gemm(const float* __restrict__ W2,
                                              const float* __restrict__ b2,
                                              const float* __restrict__ h1,
                                              float* __restrict__ edc)
{
    __shared__ float w2f[8192];                            // 32 KB: [row(32)][col(256)]
    __shared__ __align__(16) unsigned short afr[4096];     // 8 KB: [bt(4)][kb(2)][lane][e]
    int tid = threadIdx.x;
    long C0 = (long)blockIdx.x * 256;
    float4 z4 = make_float4(0.f, 0.f, 0.f, 0.f);

    // stage A fragments (block-invariant, one slot per thread)
    {
        int bt = tid >> 7, kb = (tid >> 6) & 1, l = tid & 63;
        int q = l >> 4, r = l & 15;
        unsigned short hh[8];
        #pragma unroll
        for (int e = 0; e < 8; ++e)
            hh[e] = f2bu(h1[(32 * kb + 8 * q + e) * 64 + 16 * bt + r]);
        *(uint4*)(&afr[tid * 8]) = pack8(hh);
    }
    // stage w2f chunk kb=0 (rows 0..31), coalesced float4
    #pragma unroll
    for (int s = 0; s < 4; ++s) {
        int slot = tid + 512 * s;
        int row = slot >> 6, c4 = slot & 63;
        long col = C0 + 4 * c4;
        float4 v = (col < LJ) ? *(const float4*)(W2 + (long)row * LJ + col) : z4;
        *(float4*)(&w2f[row * 256 + 4 * c4]) = v;
    }
    __syncthreads();

    int lane = tid & 63, wv = tid >> 6;
    int q = lane >> 4, r = lane & 15;
    f32x4 acc[2][4];
    #pragma unroll
    for (int c = 0; c < 2; ++c)
        #pragma unroll
        for (int b = 0; b < 4; ++b) acc[c][b] = (f32x4){0.f, 0.f, 0.f, 0.f};

    // MFMA kb=0
    #pragma unroll
    for (int ctl = 0; ctl < 2; ++ctl) {
        int ct = wv * 2 + ctl;
        unsigned short hh[8];
        #pragma unroll
        for (int e = 0; e < 8; ++e)
            hh[e] = f2bu(w2f[(8 * q + e) * 256 + 16 * ct + r]);
        uint4 braw = pack8(hh);
        #pragma unroll
        for (int bt = 0; bt < 4; ++bt) {
            uint4 araw = *(const uint4*)(&afr[((bt * 2 + 0) * 64 + lane) * 8]);
            acc[ctl][bt] = mfma16(araw, braw, acc[ctl][bt]);
        }
    }
    __syncthreads();
    // stage w2f chunk kb=1 (rows 32..63)
    #pragma unroll
    for (int s = 0; s < 4; ++s) {
        int slot = tid + 512 * s;
        int row = slot >> 6, c4 = slot & 63;
        long col = C0 + 4 * c4;
        float4 v = (col < LJ) ? *(const float4*)(W2 + (long)(32 + row) * LJ + col) : z4;
        *(float4*)(&w2f[row * 256 + 4 * c4]) = v;
    }
    __syncthreads();
    // MFMA kb=1
    #pragma unroll
    for (int ctl = 0; ctl < 2; ++ctl) {
        int ct = wv * 2 + ctl;
        unsigned short hh[8];
        #pragma unroll
        for (int e = 0; e < 8; ++e)
            hh[e] = f2bu(w2f[(8 * q + e) * 256 + 16 * ct + r]);
        uint4 braw = pack8(hh);
        #pragma unroll
        for (int bt = 0; bt < 4; ++bt) {
            uint4 araw = *(const uint4*)(&afr[((bt * 2 + 1) * 64 + lane) * 8]);
            acc[ctl][bt] = mfma16(araw, braw, acc[ctl][bt]);
        }
    }

    // epilogue: edc stores only
    #pragma unroll
    for (int ctl = 0; ctl < 2; ++ctl) {
        int ct = wv * 2 + ctl;
        long col = C0 + 16 * ct + r;
        if (col < LJ) {
            float bias = b2[col];
            #pragma unroll
            for (int bt = 0; bt < 4; ++bt)
                #pragma unroll
                for (int rg = 0; rg < 4; ++rg)
                    edc[(long)(16 * bt + 4 * q + rg) * LJ + col] = acc[ctl][bt][rg] + bias;
        }
    }
}

// ---- exact-f32 edc1d + per-block band col-sums (W2 re-read hits L3) ---------------------------
__global__ __launch_bounds__(256) void k_e1d(const float* __restrict__ W2,
                                             const float* __restrict__ b2,
                                             const float* __restrict__ h1,
                                             float* __restrict__ edc1d,
                                             float* __restrict__ wbP)
{
    __shared__ float h1T[64 * 68];                 // 17.4 KB [b][i]
    __shared__ float wbndT[32 * 68];               // 8.7 KB  [tl][i]
    int tid = threadIdx.x;
    long C0 = (long)blockIdx.x * 256;

    // stage h1 transposed
    #pragma unroll
    for (int s = 0; s < 16; ++s) {
        int g = tid + 256 * s;
        h1T[(g & 63) * 68 + (g >> 6)] = h1[g];
    }
    // band sums: each (i, tl) reads its 8 cols of W2 (L3-hot), makes wbndT + wbP
    #pragma unroll
    for (int s = 0; s < 8; ++s) {
        int e = tid + 256 * s;                     // 2048 entries
        int i = e >> 5, tl = e & 31;
        long c8 = C0 + 8 * tl;
        float v0 = 0.f, v1 = 0.f, v2 = 0.f, v3 = 0.f, v4 = 0.f, v5 = 0.f, v6 = 0.f, v7 = 0.f;
        if (c8 + 7 < LJ) {
            float4 u0 = *(const float4*)(W2 + (long)i * LJ + c8);
            float4 u1 = *(const float4*)(W2 + (long)i * LJ + c8 + 4);
            v0 = u0.x; v1 = u0.y; v2 = u0.z; v3 = u0.w;
            v4 = u1.x; v5 = u1.y; v6 = u1.z; v7 = u1.w;
        }
        wbndT[tl * 68 + i] = ((v0 + v1) + (v2 + v3)) + ((v4 + v5) + (v6 + v7));
        // per-band reduce over the 32-thread tl-group (half-wave shfl)
        float bv[8] = {v0, v1, v2, v3, v4, v5, v6, v7};
        #pragma unroll
        for (int m = 1; m < 32; m <<= 1)
            #pragma unroll
            for (int bd = 0; bd < 8; ++bd)
                bv[bd] += __shfl_xor(bv[bd], m);
        if (tl == 0) {
            #pragma unroll
            for (int bd = 0; bd < 8; ++bd)
                wbP[(long)blockIdx.x * 512 + i * 8 + bd] = bv[bd];
        }
    }
    __syncthreads();

    // dot: thread owns column tl, batches b0 + 8k
    int tl = tid & 31;
    int b0 = tid >> 5;                             // 0..7
    long c8 = C0 + 8 * tl;
    if (c8 + 7 < LJ) {
        float4 bb0 = *(const float4*)(b2 + c8);
        float4 bb1 = *(const float4*)(b2 + c8 + 4);
        float bias = ((bb0.x + bb0.y) + (bb0.z + bb0.w)) + ((bb1.x + bb1.y) + (bb1.z + bb1.w));
        float d[8];
        #pragma unroll
        for (int k = 0; k < 8; ++k) d[k] = bias;
        #pragma unroll
        for (int i0 = 0; i0 < 64; i0 += 4) {
            float4 wA = *(const float4*)(&wbndT[tl * 68 + i0]);
            #pragma unroll
            for (int k = 0; k < 8; ++k) {
                float4 hA = *(const float4*)(&h1T[(b0 + 8 * k) * 68 + i0]);
                d[k] += hA.x * wA.x + hA.y * wA.y + hA.z * wA.z + hA.w * wA.w;
            }
        }
        int tcol = (int)(C0 >> 3) + tl;
        #pragma unroll
        for (int k = 0; k < 8; ++k)
            edc1d[(long)(b0 + 8 * k) * TN + tcol] = d[k] * 0.125f;
    }
}

// ---- parallel reduce of wbP over blocks: 512 blocks, one (i,band) entry each ------------------
__global__ __launch_bounds__(64) void k_wbred(const float* __restrict__ wbP,
                                              float* __restrict__ wbL)
{
    int e = blockIdx.x;                            // entry 0..511
    int lane = threadIdx.x;
    float all = 0.f, q1 = 0.f, q4 = 0.f;
    for (int blk = lane; blk < 1001; blk += 64) {
        float v = wbP[(long)blk * 512 + e];
        all += v;
        if (blk < 250) q1 += v;
        if (blk >= 750) q4 += v;
    }
    #pragma unroll
    for (int m = 1; m < 64; m <<= 1) {
        all += __shfl_xor(all, m);
        q1  += __shfl_xor(q1, m);
        q4  += __shfl_xor(q4, m);
    }
    if (lane == 0) {
        wbL[e] = all;
        wbL[512 + e] = q1;
        wbL[1024 + e] = q4;
    }
}

// ---- final combine: sums[b][band][cls] = b2 band sums + h1 . wbL --------------------------------
__global__ __launch_bounds__(512) void k_sums2(const float* __restrict__ wbL,
                                               const float* __restrict__ b2,
                                               const float* __restrict__ h1,
                                               float* __restrict__ sums)
{
    __shared__ float wbs[1536];
    __shared__ float bsum[24];                     // [band*3+cls]
    int tid = threadIdx.x;
    wbs[tid] = wbL[tid];
    wbs[512 + tid] = wbL[512 + tid];
    wbs[1024 + tid] = wbL[1024 + tid];
    if (tid < 24) bsum[tid] = 0.f;
    __syncthreads();
    {   // b2 band-class sums
        float a[8] = {0,0,0,0,0,0,0,0}, s1[8] = {0,0,0,0,0,0,0,0}, s4[8] = {0,0,0,0,0,0,0,0};
        for (int t = tid; t <= 32000; t += 512) {
            float4 u0 = *(const float4*)(b2 + 8 * t);
            float4 u1 = *(const float4*)(b2 + 8 * t + 4);
            float vv[8] = {u0.x, u0.y, u0.z, u0.w, u1.x, u1.y, u1.z, u1.w};
            #pragma unroll
            for (int bd = 0; bd < 8; ++bd) {
                a[bd] += vv[bd];
                if (t < 8000) s1[bd] += vv[bd];
                if (t >= 24000) s4[bd] += vv[bd];
            }
        }
        #pragma unroll
        for (int bd = 0; bd < 8; ++bd) {
            atomicAdd(&bsum[bd * 3 + 0], a[bd]);
            atomicAdd(&bsum[bd * 3 + 1], s1[bd]);
            atomicAdd(&bsum[bd * 3 + 2], s4[bd]);
        }
    }
    __syncthreads();
    {
        int b = tid >> 3, band = tid & 7;
        float accA = bsum[band * 3 + 0];
        float acc1 = bsum[band * 3 + 1];
        float acc4 = bsum[band * 3 + 2];
        for (int i = 0; i < 64; ++i) {
            float h = h1[i * 64 + b];
            accA += h * wbs[i * 8 + band];
            acc1 += h * wbs[512 + i * 8 + band];
            acc4 += h * wbs[1024 + i * 8 + band];
        }
        sums[b * 24 + band * 3 + 0] = accA;
        sums[b * 24 + band * 3 + 1] = acc1;
        sums[b * 24 + band * 3 + 2] = acc4;
    }
}

// ---------------- small MLP head: one block per batch row, f32 outputs ----------------
__global__ __launch_bounds__(64) void k_mlp(const float* __restrict__ x,
    const float* __restrict__ sums,
    const float* __restrict__ eW1, const float* __restrict__ eb1,
    const float* __restrict__ eW2, const float* __restrict__ eb2,
    const float* __restrict__ dW1, const float* __restrict__ db1,
    const float* __restrict__ dW2, const float* __restrict__ db2,
    const float* __restrict__ aW1, const float* __restrict__ ab1,
    const float* __restrict__ aW2, const float* __restrict__ ab2,
    const float* __restrict__ bW1, const float* __restrict__ bb1,
    const float* __restrict__ bW2, const float* __restrict__ bb2,
    float* __restrict__ out_lk, float* __restrict__ out_a, float* __restrict__ out_b)
{
    int b = blockIdx.x, o = threadIdx.x;
    __shared__ float feat[16], a1[64], hh[64], t1[64];
    if (o < 16) {
        float v;
        if (o < 8) v = sums[b * 24 + o * 3] * (1.f / 32001.f);
        else {
            int band = o - 8;
            v = sums[b * 24 + band * 3 + 2] * (1.f / 8001.f)
              - sums[b * 24 + band * 3 + 1] * (1.f / 8000.f);
        }
        feat[o] = v;
    }
    __syncthreads();
    {   float acc = eb1[o];
        #pragma unroll
        for (int c = 0; c < 16; ++c) acc += feat[c] * eW1[c * 64 + o];
        a1[o] = fmaxf(acc, 0.f); }
    __syncthreads();
    {   float acc = eb2[o];
        for (int c = 0; c < 64; ++c) acc += a1[c] * eW2[c * 64 + o];
        hh[o] = fmaxf(acc, 0.f); }
    __syncthreads();
    {   float acc = db1[o];
        #pragma unroll
        for (int c = 0; c < 3; ++c) acc += x[b * 16 + c] * dW1[c * 64 + o];
        for (int c = 0; c < 64; ++c) acc += hh[c] * dW1[(3 + c) * 64 + o];
        t1[o] = fmaxf(acc, 0.f); }
    __syncthreads();
    if (o < 16) {
        float acc = db2[o];
        for (int c = 0; c < 64; ++c) acc += t1[c] * dW2[c * 16 + o];
        out_lk[b * 16 + o] = acc;
    }
    __syncthreads();
    if (o < 32) {
        float acc = ab1[o];
        for (int c = 0; c < 64; ++c) acc += hh[c] * aW1[c * 32 + o];
        t1[o] = fmaxf(acc, 0.f);
    }
    __syncthreads();
    if (o < 16) {
        float acc = ab2[o];
        for (int c = 0; c < 32; ++c) acc += t1[c] * aW2[c * 16 + o];
        out_a[b * 16 + o] = acc;
    }
    __syncthreads();
    if (o < 32) {
        float acc = bb1[o];
        for (int c = 0; c < 64; ++c) acc += hh[c] * bW1[c * 32 + o];
        t1[o] = fmaxf(acc, 0.f);
    }
    __syncthreads();
    if (o < 16) {
        float acc = bb2[o];
        for (int c = 0; c < 32; ++c) acc += t1[c] * bW2[c * 16 + o];
        out_b[b * 16 + o] = acc;
    }
}

// ---------------- parity stage 1: packed bits (per-(b, 256-chunk) inclusive XOR scan) ----------
__global__ __launch_bounds__(256) void k_par1(const int* __restrict__ flips,
                                              unsigned* __restrict__ parbits,
                                              unsigned* __restrict__ ctot)
{
    int b = blockIdx.x, c = blockIdx.y, tid = threadIdx.x;
    int t = c * 256 + tid;
    int bit = (t == 0) ? 0 : (flips[(long)b * OUT_LEN + t] & 1);
    int lane = tid & 63, wv = tid >> 6;
    unsigned long long mask = __ballot(bit != 0);
    int below = ((int)__popcll(mask & ((1ull << lane) - 1ull))) & 1;
    int incl = below ^ bit;
    __shared__ int wtot[4];
    if (lane == 0) wtot[wv] = ((int)__popcll(mask)) & 1;
    __syncthreads();
    int pre = 0;
    for (int w = 0; w < wv; ++w) pre ^= wtot[w];
    int inclB = pre ^ incl;
    unsigned long long m2 = __ballot(inclB != 0);
    if (lane == 0)  parbits[b * 1000 + c * 8 + wv * 2 + 0] = (unsigned)(m2 & 0xffffffffull);
    if (lane == 32) parbits[b * 1000 + c * 8 + wv * 2 + 1] = (unsigned)(m2 >> 32);
    if (tid == 0) ctot[c * 64 + b] = (unsigned)(wtot[0] ^ wtot[1] ^ wtot[2] ^ wtot[3]);
}

// ---------------- parity stage 2: exclusive prefix over chunks ----------------
__global__ __launch_bounds__(64) void k_par2(const unsigned* __restrict__ ctot,
                                             unsigned* __restrict__ cpref)
{
    int b = threadIdx.x;
    unsigned carry = 0;
    for (int c = 0; c < 125; ++c) {
        cpref[c * 64 + b] = carry;
        carry ^= ctot[c * 64 + b];
    }
}

// ------- MFMA Toeplitz conv (late+early) + amp + sign -> rir ----------------------------------
__global__ __launch_bounds__(512) void k_convm(const float* __restrict__ edc1d,
    const float* __restrict__ lk, const float* __restrict__ eg,
    const unsigned* __restrict__ parbits, const unsigned* __restrict__ cpref,
    float* __restrict__ rir)
{
    __shared__ float kerf[1024];
    __shared__ __align__(16) unsigned short afr[33 * 64 * 8];  // A frags [kb][lane][e]
    __shared__ __align__(16) unsigned short sbf[3136];         // swizzled bf16 window
    __shared__ float sf32[2049];
    int b = blockIdx.x, tb0 = blockIdx.y * 2048, tid = threadIdx.x;
    const float* src = edc1d + (long)b * TN;
    for (int k = tid; k < 1024; k += 512)
        kerf[k] = lk[k] + (k < 43 ? eg[k] : 0.f);
    for (int ch = tid; ch < 388; ch += 512) {
        unsigned short h[8];
        #pragma unroll
        for (int e = 0; e < 8; ++e) {
            int gt = tb0 + ch * 8 + e - 1031;
            float v = (gt >= 0 && gt <= OUT_LEN) ? src[gt] : 0.f;
            h[e] = f2bu(v);
        }
        int cs = ch ^ ((ch >> 3) & 7);
        *(uint4*)(&sbf[cs * 8]) = pack8(h);
    }
    for (int u = tid; u < 2049; u += 512) {
        int gt = tb0 + u;
        sf32[u] = (gt <= OUT_LEN) ? src[gt] : 0.f;
    }
    __syncthreads();
    for (int sl = tid; sl < 33 * 64; sl += 512) {
        int kb = sl >> 6, l = sl & 63;
        int x0 = kb * 32 - 1 + (l & 15) - 8 * (l >> 4);    // x = x0 - e
        unsigned short h[8];
        #pragma unroll
        for (int e = 0; e < 8; ++e) {
            int x = x0 - e;
            float v = (x >= 0 && x < 1024) ? kerf[x] : 0.f;
            h[e] = f2bu(v);
        }
        *(uint4*)(&afr[sl * 8]) = pack8(h);
    }
    __syncthreads();
    int lane = tid & 63, wv = tid >> 6;                    // 8 waves, 1 C-tile each
    int tb = tb0 + wv * 256;
    int cq = wv * 256 + 16 * (lane & 15) + 8 * (lane >> 4) + 1032;  // B chunk base (kb=0)
    f32x4 acc = {0.f, 0.f, 0.f, 0.f};
    for (int kb = 0; kb < 33; ++kb) {
        uint4 araw = *(const uint4*)(&afr[(kb * 64 + lane) * 8]);
        int ch = (cq - (kb << 5)) >> 3;
        int cs = ch ^ ((ch >> 3) & 7);
        uint4 braw = *(const uint4*)(&sbf[cs * 8]);
        acc = mfma16(araw, braw, acc);
    }
    int c = lane & 15, q = lane >> 4;
    int t4 = tb + 16 * c + 4 * q;
    if (t4 < OUT_LEN) {
        int u0 = t4 - tb0;
        unsigned pw = parbits[b * 1000 + (t4 >> 5)];       // 4 bits same word (t4%4==0)
        unsigned cp = cpref[(t4 >> 8) * 64 + b] & 1u;
        int sh = t4 & 31;
        float sv[5];
        #pragma unroll
        for (int e = 0; e < 5; ++e) sv[e] = sf32[u0 + e];
        float r[4];
        #pragma unroll
        for (int reg = 0; reg < 4; ++reg) {
            float diff = sv[reg] - sv[reg + 1];
            float amp = diff > 0.f ? sqrtf(diff) : 0.f;
            unsigned p = ((pw >> (sh + reg)) & 1u) ^ cp;
            r[reg] = acc[reg] * amp * (p ? -1.f : 1.f);
        }
        *(float4*)(rir + (long)b * OUT_LEN + t4) = make_float4(r[0], r[1], r[2], r[3]);
    }
}

extern "C" void kernel_launch(void* const* d_in, const int* in_sizes, int n_in,
                              void* d_out, int out_size, void* d_ws, size_t ws_size,
                              hipStream_t stream) {
    (void)in_sizes; (void)n_in; (void)out_size; (void)ws_size;
    const float* x    = (const float*)d_in[0];
    const float* lW1  = (const float*)d_in[1];  const float* lb1 = (const float*)d_in[2];
    const float* lW2  = (const float*)d_in[3];  const float* lb2 = (const float*)d_in[4];
    const float* eW1  = (const float*)d_in[5];  const float* eb1 = (const float*)d_in[6];
    const float* eW2  = (const float*)d_in[7];  const float* eb2 = (const float*)d_in[8];
    const float* dW1  = (const float*)d_in[9];  const float* db1 = (const float*)d_in[10];
    const float* dW2  = (const float*)d_in[11]; const float* db2 = (const float*)d_in[12];
    const float* aW1  = (const float*)d_in[13]; const float* ab1 = (const float*)d_in[14];
    const float* aW2  = (const float*)d_in[15]; const float* ab2 = (const float*)d_in[16];
    const float* bW1  = (const float*)d_in[17]; const float* bb1 = (const float*)d_in[18];
    const float* bW2  = (const float*)d_in[19]; const float* bb2 = (const float*)d_in[20];
    const float* eg   = (const float*)d_in[21]; const float* lkk = (const float*)d_in[22];
    const int* flips  = (const int*)d_in[23];

    float* out = (float*)d_out;                    // f32 output buffer
    float* rir = out;                              // 2,048,000
    float* edc = out + 2048000;                    // 16,384,512
    float* olk = out + 18432512;                   // 1,024
    float* oa  = out + 18433536;                   // 1,024
    float* ob  = out + 18434560;                   // 1,024

    // -------- ws layout (<= 10.6 MB, well under proven 18.65 MB) --------
    char* wsb = (char*)d_ws;
    float*    ws_h1   = (float*)(wsb + 1024);       // 16,384 B
    unsigned* ws_ct   = (unsigned*)(wsb + 18432);   // 32,000 B
    unsigned* ws_cp   = (unsigned*)(wsb + 50688);   // 32,000 B
    unsigned* ws_pb   = (unsigned*)(wsb + 82944);   // 256,000 B
    float*    ws_sums = (float*)(wsb + 339200);     // 6,144 B
    float*    ws_wbl  = (float*)(wsb + 345600);     // 6,144 B  (wbL: 1536 f32)
    float*    ws_e1d  = (float*)(wsb + 352256);     // 8,192,256 B -> ends 8,544,512
    float*    ws_wbp  = (float*)(wsb + 8544512);    // 1001*512*4 = 2,050,048 B -> 10,594,560

    k_h1<<<16, 256, 0, stream>>>(x, lW1, lb1, ws_h1);
    k_par1<<<dim3(64, 125), 256, 0, stream>>>(flips, ws_pb, ws_ct);
    k_par2<<<1, 64, 0, stream>>>(ws_ct, ws_cp);
    k_gemm<<<1001, 512, 0, stream>>>(lW2, lb2, ws_h1, edc);
    k_e1d<<<1001, 256, 0, stream>>>(lW2, lb2, ws_h1, ws_e1d, ws_wbp);
    k_wbred<<<512, 64, 0, stream>>>(ws_wbp, ws_wbl);
    k_sums2<<<1, 512, 0, stream>>>(ws_wbl, lb2, ws_h1, ws_sums);
    k_mlp<<<64, 64, 0, stream>>>(x, ws_sums, eW1, eb1, eW2, eb2, dW1, db1, dW2, db2,
                                 aW1, ab1, aW2, ab2, bW1, bb1, bW2, bb2, olk, oa, ob);
    k_convm<<<dim3(64, 16), 512, 0, stream>>>(ws_e1d, lkk, eg, ws_pb, ws_cp, rir);
}

// Round 24
// 146.123 us; speedup vs baseline: 1.5565x; 1.2391x over previous
//
#include <hip/hip_runtime.h>
#include <hip/hip_bf16.h>

#define LJ 256008       // T*BANDS
#define TN 32001
#define OUT_LEN 32000

typedef __attribute__((ext_vector_type(8))) short short8v;
typedef __attribute__((ext_vector_type(8))) __bf16 bf16x8;
typedef __attribute__((ext_vector_type(4))) float f32x4;

__device__ __forceinline__ unsigned short f2bu(float f) {
    union { __hip_bfloat16 h; unsigned short u; } cv; cv.h = __float2bfloat16(f); return cv.u;
}
__device__ __forceinline__ uint4 pack8(const unsigned short* h) {
    return make_uint4((unsigned)h[0] | ((unsigned)h[1] << 16),
                      (unsigned)h[2] | ((unsigned)h[3] << 16),
                      (unsigned)h[4] | ((unsigned)h[5] << 16),
                      (unsigned)h[6] | ((unsigned)h[7] << 16));
}
__device__ __forceinline__ f32x4 mfma16(uint4 a, uint4 b, f32x4 c) {
    union { uint4 u; short8v s; bf16x8 v; } ua, ub;
    ua.u = a; ub.u = b;
    return __builtin_amdgcn_mfma_f32_16x16x32_bf16(ua.v, ub.v, c, 0, 0, 0);
}

// ---------------- h1 = relu(x @ lstm_W1 + b1), stored [i][b] (f32) ----------------
__global__ __launch_bounds__(256) void k_h1(const float* __restrict__ x,
                                            const float* __restrict__ W1,
                                            const float* __restrict__ b1,
                                            float* __restrict__ h1)
{
    int idx = blockIdx.x * 256 + threadIdx.x;   // 4096 outputs
    if (idx >= 4096) return;
    int b = idx >> 6, i = idx & 63;
    float acc = b1[i];
    #pragma unroll
    for (int f = 0; f < 16; ++f)
        acc += x[b * 16 + f] * W1[f * 64 + i];
    h1[i * 64 + b] = fmaxf(acc, 0.f);
}

// ---- MFMA GEMM (pure): stage W2 chunk -> LDS, MFMA, store edc.  LDS 40KB -> 4 blocks/CU -------
__global__ __launch_bounds__(512) void k_gemm(const float* __restrict__ W2,
                                              const float* __restrict__ b2,
                                              const float* __restrict__ h1,
                                              float* __restrict__ edc)
{
    __shared__ float w2f[8192];                            // 32 KB: [row(32)][col(256)]
    __shared__ __align__(16) unsigned short afr[4096];     // 8 KB: [bt(4)][kb(2)][lane][e]
    int tid = threadIdx.x;
    long C0 = (long)blockIdx.x * 256;
    float4 z4 = make_float4(0.f, 0.f, 0.f, 0.f);

    // stage A fragments (block-invariant, one slot per thread)
    {
        int bt = tid >> 7, kb = (tid >> 6) & 1, l = tid & 63;
        int q = l >> 4, r = l & 15;
        unsigned short hh[8];
        #pragma unroll
        for (int e = 0; e < 8; ++e)
            hh[e] = f2bu(h1[(32 * kb + 8 * q + e) * 64 + 16 * bt + r]);
        *(uint4*)(&afr[tid * 8]) = pack8(hh);
    }
    // stage w2f chunk kb=0 (rows 0..31), coalesced float4
    #pragma unroll
    for (int s = 0; s < 4; ++s) {
        int slot = tid + 512 * s;
        int row = slot >> 6, c4 = slot & 63;
        long col = C0 + 4 * c4;
        float4 v = (col < LJ) ? *(const float4*)(W2 + (long)row * LJ + col) : z4;
        *(float4*)(&w2f[row * 256 + 4 * c4]) = v;
    }
    __syncthreads();

    int lane = tid & 63, wv = tid >> 6;
    int q = lane >> 4, r = lane & 15;
    f32x4 acc[2][4];
    #pragma unroll
    for (int c = 0; c < 2; ++c)
        #pragma unroll
        for (int b = 0; b < 4; ++b) acc[c][b] = (f32x4){0.f, 0.f, 0.f, 0.f};

    // MFMA kb=0
    #pragma unroll
    for (int ctl = 0; ctl < 2; ++ctl) {
        int ct = wv * 2 + ctl;
        unsigned short hh[8];
        #pragma unroll
        for (int e = 0; e < 8; ++e)
            hh[e] = f2bu(w2f[(8 * q + e) * 256 + 16 * ct + r]);
        uint4 braw = pack8(hh);
        #pragma unroll
        for (int bt = 0; bt < 4; ++bt) {
            uint4 araw = *(const uint4*)(&afr[((bt * 2 + 0) * 64 + lane) * 8]);
            acc[ctl][bt] = mfma16(araw, braw, acc[ctl][bt]);
        }
    }
    __syncthreads();
    // stage w2f chunk kb=1 (rows 32..63)
    #pragma unroll
    for (int s = 0; s < 4; ++s) {
        int slot = tid + 512 * s;
        int row = slot >> 6, c4 = slot & 63;
        long col = C0 + 4 * c4;
        float4 v = (col < LJ) ? *(const float4*)(W2 + (long)(32 + row) * LJ + col) : z4;
        *(float4*)(&w2f[row * 256 + 4 * c4]) = v;
    }
    __syncthreads();
    // MFMA kb=1
    #pragma unroll
    for (int ctl = 0; ctl < 2; ++ctl) {
        int ct = wv * 2 + ctl;
        unsigned short hh[8];
        #pragma unroll
        for (int e = 0; e < 8; ++e)
            hh[e] = f2bu(w2f[(8 * q + e) * 256 + 16 * ct + r]);
        uint4 braw = pack8(hh);
        #pragma unroll
        for (int bt = 0; bt < 4; ++bt) {
            uint4 araw = *(const uint4*)(&afr[((bt * 2 + 1) * 64 + lane) * 8]);
            acc[ctl][bt] = mfma16(araw, braw, acc[ctl][bt]);
        }
    }

    // epilogue: edc stores only
    #pragma unroll
    for (int ctl = 0; ctl < 2; ++ctl) {
        int ct = wv * 2 + ctl;
        long col = C0 + 16 * ct + r;
        if (col < LJ) {
            float bias = b2[col];
            #pragma unroll
            for (int bt = 0; bt < 4; ++bt)
                #pragma unroll
                for (int rg = 0; rg < 4; ++rg)
                    edc[(long)(16 * bt + 4 * q + rg) * LJ + col] = acc[ctl][bt][rg] + bias;
        }
    }
}

// ---- exact-f32 edc1d + per-block band col-sums (W2 re-read hits L3) ---------------------------
__global__ __launch_bounds__(256) void k_e1d(const float* __restrict__ W2,
                                             const float* __restrict__ b2,
                                             const float* __restrict__ h1,
                                             float* __restrict__ edc1d,
                                             float* __restrict__ wbP)
{
    __shared__ float h1T[64 * 68];                 // 17.4 KB [b][i]
    __shared__ float wbndT[32 * 68];               // 8.7 KB  [tl][i]
    int tid = threadIdx.x;
    long C0 = (long)blockIdx.x * 256;

    // stage h1 transposed
    #pragma unroll
    for (int s = 0; s < 16; ++s) {
        int g = tid + 256 * s;
        h1T[(g & 63) * 68 + (g >> 6)] = h1[g];
    }
    // band sums: each (i, tl) reads its 8 cols of W2 (L3-hot), makes wbndT + wbP
    #pragma unroll
    for (int s = 0; s < 8; ++s) {
        int e = tid + 256 * s;                     // 2048 entries
        int i = e >> 5, tl = e & 31;
        long c8 = C0 + 8 * tl;
        float v0 = 0.f, v1 = 0.f, v2 = 0.f, v3 = 0.f, v4 = 0.f, v5 = 0.f, v6 = 0.f, v7 = 0.f;
        if (c8 + 7 < LJ) {
            float4 u0 = *(const float4*)(W2 + (long)i * LJ + c8);
            float4 u1 = *(const float4*)(W2 + (long)i * LJ + c8 + 4);
            v0 = u0.x; v1 = u0.y; v2 = u0.z; v3 = u0.w;
            v4 = u1.x; v5 = u1.y; v6 = u1.z; v7 = u1.w;
        }
        wbndT[tl * 68 + i] = ((v0 + v1) + (v2 + v3)) + ((v4 + v5) + (v6 + v7));
        // per-band reduce over the 32-thread tl-group (half-wave shfl)
        float bv[8] = {v0, v1, v2, v3, v4, v5, v6, v7};
        #pragma unroll
        for (int m = 1; m < 32; m <<= 1)
            #pragma unroll
            for (int bd = 0; bd < 8; ++bd)
                bv[bd] += __shfl_xor(bv[bd], m);
        if (tl == 0) {
            #pragma unroll
            for (int bd = 0; bd < 8; ++bd)
                wbP[(long)blockIdx.x * 512 + i * 8 + bd] = bv[bd];
        }
    }
    __syncthreads();

    // dot: thread owns column tl, batches b0 + 8k
    int tl = tid & 31;
    int b0 = tid >> 5;                             // 0..7
    long c8 = C0 + 8 * tl;
    if (c8 + 7 < LJ) {
        float4 bb0 = *(const float4*)(b2 + c8);
        float4 bb1 = *(const float4*)(b2 + c8 + 4);
        float bias = ((bb0.x + bb0.y) + (bb0.z + bb0.w)) + ((bb1.x + bb1.y) + (bb1.z + bb1.w));
        float d[8];
        #pragma unroll
        for (int k = 0; k < 8; ++k) d[k] = bias;
        #pragma unroll
        for (int i0 = 0; i0 < 64; i0 += 4) {
            float4 wA = *(const float4*)(&wbndT[tl * 68 + i0]);
            #pragma unroll
            for (int k = 0; k < 8; ++k) {
                float4 hA = *(const float4*)(&h1T[(b0 + 8 * k) * 68 + i0]);
                d[k] += hA.x * wA.x + hA.y * wA.y + hA.z * wA.z + hA.w * wA.w;
            }
        }
        int tcol = (int)(C0 >> 3) + tl;
        #pragma unroll
        for (int k = 0; k < 8; ++k)
            edc1d[(long)(b0 + 8 * k) * TN + tcol] = d[k] * 0.125f;
    }
}

// ---- parallel reduce of wbP over blocks: 512 blocks, one (i,band) entry each ------------------
__global__ __launch_bounds__(64) void k_wbred(const float* __restrict__ wbP,
                                              float* __restrict__ wbL)
{
    int e = blockIdx.x;                            // entry 0..511
    int lane = threadIdx.x;
    float all = 0.f, q1 = 0.f, q4 = 0.f;
    for (int blk = lane; blk < 1001; blk += 64) {
        float v = wbP[(long)blk * 512 + e];
        all += v;
        if (blk < 250) q1 += v;
        if (blk >= 750) q4 += v;
    }
    #pragma unroll
    for (int m = 1; m < 64; m <<= 1) {
        all += __shfl_xor(all, m);
        q1  += __shfl_xor(q1, m);
        q4  += __shfl_xor(q4, m);
    }
    if (lane == 0) {
        wbL[e] = all;
        wbL[512 + e] = q1;
        wbL[1024 + e] = q4;
    }
}

// ---- parallel b2 band-class sums: 8 blocks (one per band) x 256 threads -----------------------
__global__ __launch_bounds__(256) void k_b2red(const float* __restrict__ b2,
                                               float* __restrict__ b2X)
{
    int band = blockIdx.x, tid = threadIdx.x;
    float a = 0.f, s1 = 0.f, s4 = 0.f;
    for (int t = tid; t < TN; t += 256) {
        float v = b2[8 * t + band];
        a += v;
        if (t < 8000) s1 += v;
        if (t >= 24000) s4 += v;
    }
    #pragma unroll
    for (int m = 1; m < 64; m <<= 1) {
        a  += __shfl_xor(a, m);
        s1 += __shfl_xor(s1, m);
        s4 += __shfl_xor(s4, m);
    }
    __shared__ float red[12];
    int lane = tid & 63, wv = tid >> 6;
    if (lane == 0) { red[wv * 3 + 0] = a; red[wv * 3 + 1] = s1; red[wv * 3 + 2] = s4; }
    __syncthreads();
    if (tid == 0) {
        b2X[band * 3 + 0] = red[0] + red[3] + red[6] + red[9];
        b2X[band * 3 + 1] = red[1] + red[4] + red[7] + red[10];
        b2X[band * 3 + 2] = red[2] + red[5] + red[8] + red[11];
    }
}

// ---------------- MLP head with fused sums: one block per batch row, f32 outputs ---------------
__global__ __launch_bounds__(64) void k_mlp(const float* __restrict__ x,
    const float* __restrict__ wbL, const float* __restrict__ b2X,
    const float* __restrict__ h1,
    const float* __restrict__ eW1, const float* __restrict__ eb1,
    const float* __restrict__ eW2, const float* __restrict__ eb2,
    const float* __restrict__ dW1, const float* __restrict__ db1,
    const float* __restrict__ dW2, const float* __restrict__ db2,
    const float* __restrict__ aW1, const float* __restrict__ ab1,
    const float* __restrict__ aW2, const float* __restrict__ ab2,
    const float* __restrict__ bW1, const float* __restrict__ bb1,
    const float* __restrict__ bW2, const float* __restrict__ bb2,
    float* __restrict__ out_lk, float* __restrict__ out_a, float* __restrict__ out_b)
{
    int b = blockIdx.x, o = threadIdx.x;
    __shared__ float feat[16], a1[64], hh[64], t1[64];
    // fused sums: thread o = i holds h1[i][b]; 24 shfl-reduced dots
    {
        float h = h1[o * 64 + b];
        float sb[24];
        #pragma unroll
        for (int band = 0; band < 8; ++band) {
            sb[band * 3 + 0] = h * wbL[o * 8 + band];
            sb[band * 3 + 1] = h * wbL[512 + o * 8 + band];
            sb[band * 3 + 2] = h * wbL[1024 + o * 8 + band];
        }
        #pragma unroll
        for (int m = 1; m < 64; m <<= 1)
            #pragma unroll
            for (int j = 0; j < 24; ++j)
                sb[j] += __shfl_xor(sb[j], m);
        if (o < 16) {
            float v;
            if (o < 8) v = (sb[o * 3 + 0] + b2X[o * 3 + 0]) * (1.f / 32001.f);
            else {
                int band = o - 8;
                v = (sb[band * 3 + 2] + b2X[band * 3 + 2]) * (1.f / 8001.f)
                  - (sb[band * 3 + 1] + b2X[band * 3 + 1]) * (1.f / 8000.f);
            }
            feat[o] = v;
        }
    }
    __syncthreads();
    {   float acc = eb1[o];
        #pragma unroll
        for (int c = 0; c < 16; ++c) acc += feat[c] * eW1[c * 64 + o];
        a1[o] = fmaxf(acc, 0.f); }
    __syncthreads();
    {   float acc = eb2[o];
        for (int c = 0; c < 64; ++c) acc += a1[c] * eW2[c * 64 + o];
        hh[o] = fmaxf(acc, 0.f); }
    __syncthreads();
    {   float acc = db1[o];
        #pragma unroll
        for (int c = 0; c < 3; ++c) acc += x[b * 16 + c] * dW1[c * 64 + o];
        for (int c = 0; c < 64; ++c) acc += hh[c] * dW1[(3 + c) * 64 + o];
        t1[o] = fmaxf(acc, 0.f); }
    __syncthreads();
    if (o < 16) {
        float acc = db2[o];
        for (int c = 0; c < 64; ++c) acc += t1[c] * dW2[c * 16 + o];
        out_lk[b * 16 + o] = acc;
    }
    __syncthreads();
    if (o < 32) {
        float acc = ab1[o];
        for (int c = 0; c < 64; ++c) acc += hh[c] * aW1[c * 32 + o];
        t1[o] = fmaxf(acc, 0.f);
    }
    __syncthreads();
    if (o < 16) {
        float acc = ab2[o];
        for (int c = 0; c < 32; ++c) acc += t1[c] * aW2[c * 16 + o];
        out_a[b * 16 + o] = acc;
    }
    __syncthreads();
    if (o < 32) {
        float acc = bb1[o];
        for (int c = 0; c < 64; ++c) acc += hh[c] * bW1[c * 32 + o];
        t1[o] = fmaxf(acc, 0.f);
    }
    __syncthreads();
    if (o < 16) {
        float acc = bb2[o];
        for (int c = 0; c < 32; ++c) acc += t1[c] * bW2[c * 16 + o];
        out_b[b * 16 + o] = acc;
    }
}

// ---------------- parity stage 1: packed bits (per-(b, 256-chunk) inclusive XOR scan) ----------
__global__ __launch_bounds__(256) void k_par1(const int* __restrict__ flips,
                                              unsigned* __restrict__ parbits,
                                              unsigned* __restrict__ ctot)
{
    int b = blockIdx.x, c = blockIdx.y, tid = threadIdx.x;
    int t = c * 256 + tid;
    int bit = (t == 0) ? 0 : (flips[(long)b * OUT_LEN + t] & 1);
    int lane = tid & 63, wv = tid >> 6;
    unsigned long long mask = __ballot(bit != 0);
    int below = ((int)__popcll(mask & ((1ull << lane) - 1ull))) & 1;
    int incl = below ^ bit;
    __shared__ int wtot[4];
    if (lane == 0) wtot[wv] = ((int)__popcll(mask)) & 1;
    __syncthreads();
    int pre = 0;
    for (int w = 0; w < wv; ++w) pre ^= wtot[w];
    int inclB = pre ^ incl;
    unsigned long long m2 = __ballot(inclB != 0);
    if (lane == 0)  parbits[b * 1000 + c * 8 + wv * 2 + 0] = (unsigned)(m2 & 0xffffffffull);
    if (lane == 32) parbits[b * 1000 + c * 8 + wv * 2 + 1] = (unsigned)(m2 >> 32);
    if (tid == 0) ctot[c * 64 + b] = (unsigned)(wtot[0] ^ wtot[1] ^ wtot[2] ^ wtot[3]);
}

// ---------------- parity stage 2: exclusive prefix over chunks ----------------
__global__ __launch_bounds__(64) void k_par2(const unsigned* __restrict__ ctot,
                                             unsigned* __restrict__ cpref)
{
    int b = threadIdx.x;
    unsigned carry = 0;
    for (int c = 0; c < 125; ++c) {
        cpref[c * 64 + b] = carry;
        carry ^= ctot[c * 64 + b];
    }
}

// ------- MFMA Toeplitz conv (late+early) + amp + sign -> rir ----------------------------------
__global__ __launch_bounds__(512) void k_convm(const float* __restrict__ edc1d,
    const float* __restrict__ lk, const float* __restrict__ eg,
    const unsigned* __restrict__ parbits, const unsigned* __restrict__ cpref,
    float* __restrict__ rir)
{
    __shared__ float kerf[1024];
    __shared__ __align__(16) unsigned short afr[33 * 64 * 8];  // A frags [kb][lane][e]
    __shared__ __align__(16) unsigned short sbf[3136];         // swizzled bf16 window
    __shared__ float sf32[2049];
    int b = blockIdx.x, tb0 = blockIdx.y * 2048, tid = threadIdx.x;
    const float* src = edc1d + (long)b * TN;
    for (int k = tid; k < 1024; k += 512)
        kerf[k] = lk[k] + (k < 43 ? eg[k] : 0.f);
    for (int ch = tid; ch < 388; ch += 512) {
        unsigned short h[8];
        #pragma unroll
        for (int e = 0; e < 8; ++e) {
            int gt = tb0 + ch * 8 + e - 1031;
            float v = (gt >= 0 && gt <= OUT_LEN) ? src[gt] : 0.f;
            h[e] = f2bu(v);
        }
        int cs = ch ^ ((ch >> 3) & 7);
        *(uint4*)(&sbf[cs * 8]) = pack8(h);
    }
    for (int u = tid; u < 2049; u += 512) {
        int gt = tb0 + u;
        sf32[u] = (gt <= OUT_LEN) ? src[gt] : 0.f;
    }
    __syncthreads();
    for (int sl = tid; sl < 33 * 64; sl += 512) {
        int kb = sl >> 6, l = sl & 63;
        int x0 = kb * 32 - 1 + (l & 15) - 8 * (l >> 4);    // x = x0 - e
        unsigned short h[8];
        #pragma unroll
        for (int e = 0; e < 8; ++e) {
            int x = x0 - e;
            float v = (x >= 0 && x < 1024) ? kerf[x] : 0.f;
            h[e] = f2bu(v);
        }
        *(uint4*)(&afr[sl * 8]) = pack8(h);
    }
    __syncthreads();
    int lane = tid & 63, wv = tid >> 6;                    // 8 waves, 1 C-tile each
    int tb = tb0 + wv * 256;
    int cq = wv * 256 + 16 * (lane & 15) + 8 * (lane >> 4) + 1032;  // B chunk base (kb=0)
    f32x4 acc = {0.f, 0.f, 0.f, 0.f};
    for (int kb = 0; kb < 33; ++kb) {
        uint4 araw = *(const uint4*)(&afr[(kb * 64 + lane) * 8]);
        int ch = (cq - (kb << 5)) >> 3;
        int cs = ch ^ ((ch >> 3) & 7);
        uint4 braw = *(const uint4*)(&sbf[cs * 8]);
        acc = mfma16(araw, braw, acc);
    }
    int c = lane & 15, q = lane >> 4;
    int t4 = tb + 16 * c + 4 * q;
    if (t4 < OUT_LEN) {
        int u0 = t4 - tb0;
        unsigned pw = parbits[b * 1000 + (t4 >> 5)];       // 4 bits same word (t4%4==0)
        unsigned cp = cpref[(t4 >> 8) * 64 + b] & 1u;
        int sh = t4 & 31;
        float sv[5];
        #pragma unroll
        for (int e = 0; e < 5; ++e) sv[e] = sf32[u0 + e];
        float r[4];
        #pragma unroll
        for (int reg = 0; reg < 4; ++reg) {
            float diff = sv[reg] - sv[reg + 1];
            float amp = diff > 0.f ? sqrtf(diff) : 0.f;
            unsigned p = ((pw >> (sh + reg)) & 1u) ^ cp;
            r[reg] = acc[reg] * amp * (p ? -1.f : 1.f);
        }
        *(float4*)(rir + (long)b * OUT_LEN + t4) = make_float4(r[0], r[1], r[2], r[3]);
    }
}

extern "C" void kernel_launch(void* const* d_in, const int* in_sizes, int n_in,
                              void* d_out, int out_size, void* d_ws, size_t ws_size,
                              hipStream_t stream) {
    (void)in_sizes; (void)n_in; (void)out_size; (void)ws_size;
    const float* x    = (const float*)d_in[0];
    const float* lW1  = (const float*)d_in[1];  const float* lb1 = (const float*)d_in[2];
    const float* lW2  = (const float*)d_in[3];  const float* lb2 = (const float*)d_in[4];
    const float* eW1  = (const float*)d_in[5];  const float* eb1 = (const float*)d_in[6];
    const float* eW2  = (const float*)d_in[7];  const float* eb2 = (const float*)d_in[8];
    const float* dW1  = (const float*)d_in[9];  const float* db1 = (const float*)d_in[10];
    const float* dW2  = (const float*)d_in[11]; const float* db2 = (const float*)d_in[12];
    const float* aW1  = (const float*)d_in[13]; const float* ab1 = (const float*)d_in[14];
    const float* aW2  = (const float*)d_in[15]; const float* ab2 = (const float*)d_in[16];
    const float* bW1  = (const float*)d_in[17]; const float* bb1 = (const float*)d_in[18];
    const float* bW2  = (const float*)d_in[19]; const float* bb2 = (const float*)d_in[20];
    const float* eg   = (const float*)d_in[21]; const float* lkk = (const float*)d_in[22];
    const int* flips  = (const int*)d_in[23];

    float* out = (float*)d_out;                    // f32 output buffer
    float* rir = out;                              // 2,048,000
    float* edc = out + 2048000;                    // 16,384,512
    float* olk = out + 18432512;                   // 1,024
    float* oa  = out + 18433536;                   // 1,024
    float* ob  = out + 18434560;                   // 1,024

    // -------- ws layout (<= 10.6 MB, well under proven 18.65 MB) --------
    char* wsb = (char*)d_ws;
    float*    ws_h1   = (float*)(wsb + 1024);       // 16,384 B
    unsigned* ws_ct   = (unsigned*)(wsb + 18432);   // 32,000 B
    unsigned* ws_cp   = (unsigned*)(wsb + 50688);   // 32,000 B
    unsigned* ws_pb   = (unsigned*)(wsb + 82944);   // 256,000 B
    float*    ws_b2x  = (float*)(wsb + 339200);     // 96 B
    float*    ws_wbl  = (float*)(wsb + 345600);     // 6,144 B  (wbL: 1536 f32)
    float*    ws_e1d  = (float*)(wsb + 352256);     // 8,192,256 B -> ends 8,544,512
    float*    ws_wbp  = (float*)(wsb + 8544512);    // 1001*512*4 = 2,050,048 B -> 10,594,560

    k_h1<<<16, 256, 0, stream>>>(x, lW1, lb1, ws_h1);
    k_par1<<<dim3(64, 125), 256, 0, stream>>>(flips, ws_pb, ws_ct);
    k_par2<<<1, 64, 0, stream>>>(ws_ct, ws_cp);
    k_gemm<<<1001, 512, 0, stream>>>(lW2, lb2, ws_h1, edc);
    k_e1d<<<1001, 256, 0, stream>>>(lW2, lb2, ws_h1, ws_e1d, ws_wbp);
    k_wbred<<<512, 64, 0, stream>>>(ws_wbp, ws_wbl);
    k_b2red<<<8, 256, 0, stream>>>(lb2, ws_b2x);
    k_mlp<<<64, 64, 0, stream>>>(x, ws_wbl, ws_b2x, ws_h1,
                                 eW1, eb1, eW2, eb2, dW1, db1, dW2, db2,
                                 aW1, ab1, aW2, ab2, bW1, bb1, bW2, bb2, olk, oa, ob);
    k_convm<<<dim3(64, 16), 512, 0, stream>>>(ws_e1d, lkk, eg, ws_pb, ws_cp, rir);
}

// Round 25
// 137.577 us; speedup vs baseline: 1.6532x; 1.0621x over previous
//
#include <hip/hip_runtime.h>
#include <hip/hip_bf16.h>

#define LJ 256008       // T*BANDS
#define TN 32001
#define OUT_LEN 32000
#define WST 260         // w2f row stride (floats)

typedef __attribute__((ext_vector_type(8))) short short8v;
typedef __attribute__((ext_vector_type(8))) __bf16 bf16x8;
typedef __attribute__((ext_vector_type(4))) float f32x4;

__device__ __forceinline__ unsigned short f2bu(float f) {
    union { __hip_bfloat16 h; unsigned short u; } cv; cv.h = __float2bfloat16(f); return cv.u;
}
__device__ __forceinline__ uint4 pack8(const unsigned short* h) {
    return make_uint4((unsigned)h[0] | ((unsigned)h[1] << 16),
                      (unsigned)h[2] | ((unsigned)h[3] << 16),
                      (unsigned)h[4] | ((unsigned)h[5] << 16),
                      (unsigned)h[6] | ((unsigned)h[7] << 16));
}
__device__ __forceinline__ f32x4 mfma16(uint4 a, uint4 b, f32x4 c) {
    union { uint4 u; short8v s; bf16x8 v; } ua, ub;
    ua.u = a; ub.u = b;
    return __builtin_amdgcn_mfma_f32_16x16x32_bf16(ua.v, ub.v, c, 0, 0, 0);
}

// ---------------- h1 = relu(x @ lstm_W1 + b1), stored [i][b] (f32) ----------------
__global__ __launch_bounds__(256) void k_h1(const float* __restrict__ x,
                                            const float* __restrict__ W1,
                                            const float* __restrict__ b1,
                                            float* __restrict__ h1)
{
    int idx = blockIdx.x * 256 + threadIdx.x;   // 4096 outputs
    if (idx >= 4096) return;
    int b = idx >> 6, i = idx & 63;
    float acc = b1[i];
    #pragma unroll
    for (int f = 0; f < 16; ++f)
        acc += x[b * 16 + f] * W1[f * 64 + i];
    h1[i * 64 + b] = fmaxf(acc, 0.f);
}

// ---- Fused MFMA GEMM: edc (coalesced via LDS transpose) + exact-f32 edc1d + wbP band partials -
__global__ __launch_bounds__(512) void k_gemm(const float* __restrict__ W2,
                                              const float* __restrict__ b2,
                                              const float* __restrict__ h1,
                                              float* __restrict__ edc,
                                              float* __restrict__ edc1d,
                                              float* __restrict__ wbP)
{
    __shared__ float h1T[64 * 68];                         // 17.4 KB [b][i]
    __shared__ float w2f[32 * WST];                        // 33.3 KB [row][col] (stride 260)
    __shared__ __align__(16) unsigned short afr[4096];     // 8 KB [bt(4)][kb(2)][lane][e]
    __shared__ float wbandT[32 * 68];                      // 8.7 KB [tl][i]
    int tid = threadIdx.x;
    long C0 = (long)blockIdx.x * 256;
    float4 z4 = make_float4(0.f, 0.f, 0.f, 0.f);

    // stage h1 transposed [b][i]
    #pragma unroll
    for (int s = 0; s < 8; ++s) {
        int g = tid + 512 * s;
        h1T[(g & 63) * 68 + (g >> 6)] = h1[g];
    }
    // stage A fragments (block-invariant, one slot per thread)
    {
        int bt = tid >> 7, kb = (tid >> 6) & 1, l = tid & 63;
        int q = l >> 4, r = l & 15;
        unsigned short hh[8];
        #pragma unroll
        for (int e = 0; e < 8; ++e)
            hh[e] = f2bu(h1[(32 * kb + 8 * q + e) * 64 + 16 * bt + r]);
        *(uint4*)(&afr[tid * 8]) = pack8(hh);
    }
    // stage w2f chunk kb=0 (rows 0..31), coalesced float4
    #pragma unroll
    for (int s = 0; s < 4; ++s) {
        int slot = tid + 512 * s;
        int row = slot >> 6, c4 = slot & 63;
        long col = C0 + 4 * c4;
        float4 v = (col < LJ) ? *(const float4*)(W2 + (long)row * LJ + col) : z4;
        *(float4*)(&w2f[row * WST + 4 * c4]) = v;
    }
    __syncthreads();

    int lane = tid & 63, wv = tid >> 6;
    int q = lane >> 4, r = lane & 15;
    f32x4 acc[2][4];
    #pragma unroll
    for (int c = 0; c < 2; ++c)
        #pragma unroll
        for (int b = 0; b < 4; ++b) acc[c][b] = (f32x4){0.f, 0.f, 0.f, 0.f};

    // wbandT + wbP for rows i = 0..31
    #pragma unroll
    for (int s = 0; s < 2; ++s) {
        int en = tid + 512 * s;                    // 1024 entries: i=en>>5, tl=en&31
        int i = en >> 5, tl = en & 31;
        const float* p = &w2f[i * WST + 8 * tl];
        float bv0 = p[0], bv1 = p[1], bv2 = p[2], bv3 = p[3];
        float bv4 = p[4], bv5 = p[5], bv6 = p[6], bv7 = p[7];
        wbandT[tl * 68 + i] = ((bv0 + bv1) + (bv2 + bv3)) + ((bv4 + bv5) + (bv6 + bv7));
        #pragma unroll
        for (int m = 1; m < 32; m <<= 1) {
            bv0 += __shfl_xor(bv0, m); bv1 += __shfl_xor(bv1, m);
            bv2 += __shfl_xor(bv2, m); bv3 += __shfl_xor(bv3, m);
            bv4 += __shfl_xor(bv4, m); bv5 += __shfl_xor(bv5, m);
            bv6 += __shfl_xor(bv6, m); bv7 += __shfl_xor(bv7, m);
        }
        if (tl == 0) {
            float* wp = wbP + (long)blockIdx.x * 512 + i * 8;
            wp[0] = bv0; wp[1] = bv1; wp[2] = bv2; wp[3] = bv3;
            wp[4] = bv4; wp[5] = bv5; wp[6] = bv6; wp[7] = bv7;
        }
    }
    // MFMA kb=0
    #pragma unroll
    for (int ctl = 0; ctl < 2; ++ctl) {
        int ct = wv * 2 + ctl;
        unsigned short hh[8];
        #pragma unroll
        for (int e = 0; e < 8; ++e)
            hh[e] = f2bu(w2f[(8 * q + e) * WST + 16 * ct + r]);
        uint4 braw = pack8(hh);
        #pragma unroll
        for (int bt = 0; bt < 4; ++bt) {
            uint4 araw = *(const uint4*)(&afr[((bt * 2 + 0) * 64 + lane) * 8]);
            acc[ctl][bt] = mfma16(araw, braw, acc[ctl][bt]);
        }
    }
    __syncthreads();                               // done reading w2f(kb0)
    // stage w2f chunk kb=1 (rows 32..63)
    #pragma unroll
    for (int s = 0; s < 4; ++s) {
        int slot = tid + 512 * s;
        int row = slot >> 6, c4 = slot & 63;
        long col = C0 + 4 * c4;
        float4 v = (col < LJ) ? *(const float4*)(W2 + (long)(32 + row) * LJ + col) : z4;
        *(float4*)(&w2f[row * WST + 4 * c4]) = v;
    }
    __syncthreads();
    // wbandT + wbP for rows i = 32..63
    #pragma unroll
    for (int s = 0; s < 2; ++s) {
        int en = tid + 512 * s;
        int i2 = en >> 5, tl = en & 31;
        const float* p = &w2f[i2 * WST + 8 * tl];
        float bv0 = p[0], bv1 = p[1], bv2 = p[2], bv3 = p[3];
        float bv4 = p[4], bv5 = p[5], bv6 = p[6], bv7 = p[7];
        wbandT[tl * 68 + 32 + i2] = ((bv0 + bv1) + (bv2 + bv3)) + ((bv4 + bv5) + (bv6 + bv7));
        #pragma unroll
        for (int m = 1; m < 32; m <<= 1) {
            bv0 += __shfl_xor(bv0, m); bv1 += __shfl_xor(bv1, m);
            bv2 += __shfl_xor(bv2, m); bv3 += __shfl_xor(bv3, m);
            bv4 += __shfl_xor(bv4, m); bv5 += __shfl_xor(bv5, m);
            bv6 += __shfl_xor(bv6, m); bv7 += __shfl_xor(bv7, m);
        }
        if (tl == 0) {
            float* wp = wbP + (long)blockIdx.x * 512 + (32 + i2) * 8;
            wp[0] = bv0; wp[1] = bv1; wp[2] = bv2; wp[3] = bv3;
            wp[4] = bv4; wp[5] = bv5; wp[6] = bv6; wp[7] = bv7;
        }
    }
    // MFMA kb=1
    #pragma unroll
    for (int ctl = 0; ctl < 2; ++ctl) {
        int ct = wv * 2 + ctl;
        unsigned short hh[8];
        #pragma unroll
        for (int e = 0; e < 8; ++e)
            hh[e] = f2bu(w2f[(8 * q + e) * WST + 16 * ct + r]);
        uint4 braw = pack8(hh);
        #pragma unroll
        for (int bt = 0; bt < 4; ++bt) {
            uint4 araw = *(const uint4*)(&afr[((bt * 2 + 1) * 64 + lane) * 8]);
            acc[ctl][bt] = mfma16(araw, braw, acc[ctl][bt]);
        }
    }
    __syncthreads();                               // wbandT complete; w2f free

    // exact-f32 edc1d (R20 dot): thread owns column tl, batches b0+16s
    {
        int tl = tid & 31;
        int b0 = tid >> 5;                         // 0..15
        long c8 = C0 + 8 * tl;
        if (c8 + 7 < LJ) {
            float4 bb0 = *(const float4*)(b2 + c8);
            float4 bb1 = *(const float4*)(b2 + c8 + 4);
            float bias = ((bb0.x + bb0.y) + (bb0.z + bb0.w)) + ((bb1.x + bb1.y) + (bb1.z + bb1.w));
            float d0 = bias, d1 = bias, d2 = bias, d3 = bias;
            #pragma unroll
            for (int i0 = 0; i0 < 64; i0 += 4) {
                float4 wA = *(const float4*)(&wbandT[tl * 68 + i0]);
                {
                    float4 hA = *(const float4*)(&h1T[(b0 +  0) * 68 + i0]);
                    d0 += hA.x*wA.x + hA.y*wA.y + hA.z*wA.z + hA.w*wA.w;
                }
                {
                    float4 hA = *(const float4*)(&h1T[(b0 + 16) * 68 + i0]);
                    d1 += hA.x*wA.x + hA.y*wA.y + hA.z*wA.z + hA.w*wA.w;
                }
                {
                    float4 hA = *(const float4*)(&h1T[(b0 + 32) * 68 + i0]);
                    d2 += hA.x*wA.x + hA.y*wA.y + hA.z*wA.z + hA.w*wA.w;
                }
                {
                    float4 hA = *(const float4*)(&h1T[(b0 + 48) * 68 + i0]);
                    d3 += hA.x*wA.x + hA.y*wA.y + hA.z*wA.z + hA.w*wA.w;
                }
            }
            int tcol = (int)(C0 >> 3) + tl;
            edc1d[(long)(b0 +  0) * TN + tcol] = d0 * 0.125f;
            edc1d[(long)(b0 + 16) * TN + tcol] = d1 * 0.125f;
            edc1d[(long)(b0 + 32) * TN + tcol] = d2 * 0.125f;
            edc1d[(long)(b0 + 48) * TN + tcol] = d3 * 0.125f;
        }
    }

    // epilogue: transpose acc through w2f -> fully-coalesced float4 edc stores, 2 passes
    float biasv[2];
    #pragma unroll
    for (int ctl = 0; ctl < 2; ++ctl) {
        long col = C0 + 16 * (wv * 2 + ctl) + r;
        biasv[ctl] = (col < LJ) ? b2[col] : 0.f;
    }
    #pragma unroll
    for (int pass = 0; pass < 2; ++pass) {         // pass 0: batches 0..31, pass 1: 32..63
        __syncthreads();                           // w2f free from previous use
        #pragma unroll
        for (int ctl = 0; ctl < 2; ++ctl) {
            int ct = wv * 2 + ctl;
            #pragma unroll
            for (int btl = 0; btl < 2; ++btl) {
                int bt = pass * 2 + btl;
                #pragma unroll
                for (int rg = 0; rg < 4; ++rg)
                    w2f[(16 * btl + 4 * q + rg) * WST + 16 * ct + r]
                        = acc[ctl][bt][rg] + biasv[ctl];
            }
        }
        __syncthreads();
        #pragma unroll
        for (int s = 0; s < 4; ++s) {
            int slot = tid + 512 * s;
            int row = slot >> 6, c4 = slot & 63;   // row const per wave -> coalesced
            long col = C0 + 4 * c4;
            if (col < LJ)
                *(float4*)(edc + (long)(pass * 32 + row) * LJ + col)
                    = *(const float4*)(&w2f[row * WST + 4 * c4]);
        }
    }
}

// ---- parallel reduce of wbP over blocks: 512 blocks, one (i,band) entry each ------------------
__global__ __launch_bounds__(64) void k_wbred(const float* __restrict__ wbP,
                                              float* __restrict__ wbL)
{
    int e = blockIdx.x;                            // entry 0..511
    int lane = threadIdx.x;
    float all = 0.f, q1 = 0.f, q4 = 0.f;
    for (int blk = lane; blk < 1001; blk += 64) {
        float v = wbP[(long)blk * 512 + e];
        all += v;
        if (blk < 250) q1 += v;
        if (blk >= 750) q4 += v;
    }
    #pragma unroll
    for (int m = 1; m < 64; m <<= 1) {
        all += __shfl_xor(all, m);
        q1  += __shfl_xor(q1, m);
        q4  += __shfl_xor(q4, m);
    }
    if (lane == 0) {
        wbL[e] = all;
        wbL[512 + e] = q1;
        wbL[1024 + e] = q4;
    }
}

// ---- parallel b2 band-class sums: 8 blocks (one per band) x 256 threads -----------------------
__global__ __launch_bounds__(256) void k_b2red(const float* __restrict__ b2,
                                               float* __restrict__ b2X)
{
    int band = blockIdx.x, tid = threadIdx.x;
    float a = 0.f, s1 = 0.f, s4 = 0.f;
    for (int t = tid; t < TN; t += 256) {
        float v = b2[8 * t + band];
        a += v;
        if (t < 8000) s1 += v;
        if (t >= 24000) s4 += v;
    }
    #pragma unroll
    for (int m = 1; m < 64; m <<= 1) {
        a  += __shfl_xor(a, m);
        s1 += __shfl_xor(s1, m);
        s4 += __shfl_xor(s4, m);
    }
    __shared__ float red[12];
    int lane = tid & 63, wv = tid >> 6;
    if (lane == 0) { red[wv * 3 + 0] = a; red[wv * 3 + 1] = s1; red[wv * 3 + 2] = s4; }
    __syncthreads();
    if (tid == 0) {
        b2X[band * 3 + 0] = red[0] + red[3] + red[6] + red[9];
        b2X[band * 3 + 1] = red[1] + red[4] + red[7] + red[10];
        b2X[band * 3 + 2] = red[2] + red[5] + red[8] + red[11];
    }
}

// ---------------- MLP head with fused sums: one block per batch row, f32 outputs ---------------
__global__ __launch_bounds__(64) void k_mlp(const float* __restrict__ x,
    const float* __restrict__ wbL, const float* __restrict__ b2X,
    const float* __restrict__ h1,
    const float* __restrict__ eW1, const float* __restrict__ eb1,
    const float* __restrict__ eW2, const float* __restrict__ eb2,
    const float* __restrict__ dW1, const float* __restrict__ db1,
    const float* __restrict__ dW2, const float* __restrict__ db2,
    const float* __restrict__ aW1, const float* __restrict__ ab1,
    const float* __restrict__ aW2, const float* __restrict__ ab2,
    const float* __restrict__ bW1, const float* __restrict__ bb1,
    const float* __restrict__ bW2, const float* __restrict__ bb2,
    float* __restrict__ out_lk, float* __restrict__ out_a, float* __restrict__ out_b)
{
    int b = blockIdx.x, o = threadIdx.x;
    __shared__ float feat[16], a1[64], hh[64], t1[64];
    {
        float h = h1[o * 64 + b];
        float sb[24];
        #pragma unroll
        for (int band = 0; band < 8; ++band) {
            sb[band * 3 + 0] = h * wbL[o * 8 + band];
            sb[band * 3 + 1] = h * wbL[512 + o * 8 + band];
            sb[band * 3 + 2] = h * wbL[1024 + o * 8 + band];
        }
        #pragma unroll
        for (int m = 1; m < 64; m <<= 1)
            #pragma unroll
            for (int j = 0; j < 24; ++j)
                sb[j] += __shfl_xor(sb[j], m);
        if (o < 16) {
            float v;
            if (o < 8) v = (sb[o * 3 + 0] + b2X[o * 3 + 0]) * (1.f / 32001.f);
            else {
                int band = o - 8;
                v = (sb[band * 3 + 2] + b2X[band * 3 + 2]) * (1.f / 8001.f)
                  - (sb[band * 3 + 1] + b2X[band * 3 + 1]) * (1.f / 8000.f);
            }
            feat[o] = v;
        }
    }
    __syncthreads();
    {   float acc = eb1[o];
        #pragma unroll
        for (int c = 0; c < 16; ++c) acc += feat[c] * eW1[c * 64 + o];
        a1[o] = fmaxf(acc, 0.f); }
    __syncthreads();
    {   float acc = eb2[o];
        for (int c = 0; c < 64; ++c) acc += a1[c] * eW2[c * 64 + o];
        hh[o] = fmaxf(acc, 0.f); }
    __syncthreads();
    {   float acc = db1[o];
        #pragma unroll
        for (int c = 0; c < 3; ++c) acc += x[b * 16 + c] * dW1[c * 64 + o];
        for (int c = 0; c < 64; ++c) acc += hh[c] * dW1[(3 + c) * 64 + o];
        t1[o] = fmaxf(acc, 0.f); }
    __syncthreads();
    if (o < 16) {
        float acc = db2[o];
        for (int c = 0; c < 64; ++c) acc += t1[c] * dW2[c * 16 + o];
        out_lk[b * 16 + o] = acc;
    }
    __syncthreads();
    if (o < 32) {
        float acc = ab1[o];
        for (int c = 0; c < 64; ++c) acc += hh[c] * aW1[c * 32 + o];
        t1[o] = fmaxf(acc, 0.f);
    }
    __syncthreads();
    if (o < 16) {
        float acc = ab2[o];
        for (int c = 0; c < 32; ++c) acc += t1[c] * aW2[c * 16 + o];
        out_a[b * 16 + o] = acc;
    }
    __syncthreads();
    if (o < 32) {
        float acc = bb1[o];
        for (int c = 0; c < 64; ++c) acc += hh[c] * bW1[c * 32 + o];
        t1[o] = fmaxf(acc, 0.f);
    }
    __syncthreads();
    if (o < 16) {
        float acc = bb2[o];
        for (int c = 0; c < 32; ++c) acc += t1[c] * bW2[c * 16 + o];
        out_b[b * 16 + o] = acc;
    }
}

// ---------------- parity stage 1: packed bits (per-(b, 256-chunk) inclusive XOR scan) ----------
__global__ __launch_bounds__(256) void k_par1(const int* __restrict__ flips,
                                              unsigned* __restrict__ parbits,
                                              unsigned* __restrict__ ctot)
{
    int b = blockIdx.x, c = blockIdx.y, tid = threadIdx.x;
    int t = c * 256 + tid;
    int bit = (t == 0) ? 0 : (flips[(long)b * OUT_LEN + t] & 1);
    int lane = tid & 63, wv = tid >> 6;
    unsigned long long mask = __ballot(bit != 0);
    int below = ((int)__popcll(mask & ((1ull << lane) - 1ull))) & 1;
    int incl = below ^ bit;
    __shared__ int wtot[4];
    if (lane == 0) wtot[wv] = ((int)__popcll(mask)) & 1;
    __syncthreads();
    int pre = 0;
    for (int w = 0; w < wv; ++w) pre ^= wtot[w];
    int inclB = pre ^ incl;
    unsigned long long m2 = __ballot(inclB != 0);
    if (lane == 0)  parbits[b * 1000 + c * 8 + wv * 2 + 0] = (unsigned)(m2 & 0xffffffffull);
    if (lane == 32) parbits[b * 1000 + c * 8 + wv * 2 + 1] = (unsigned)(m2 >> 32);
    if (tid == 0) ctot[c * 64 + b] = (unsigned)(wtot[0] ^ wtot[1] ^ wtot[2] ^ wtot[3]);
}

// ---------------- parity stage 2: exclusive prefix over chunks ----------------
__global__ __launch_bounds__(64) void k_par2(const unsigned* __restrict__ ctot,
                                             unsigned* __restrict__ cpref)
{
    int b = threadIdx.x;
    unsigned carry = 0;
    for (int c = 0; c < 125; ++c) {
        cpref[c * 64 + b] = carry;
        carry ^= ctot[c * 64 + b];
    }
}

// ------- MFMA Toeplitz conv (late+early) + amp + sign -> rir ----------------------------------
__global__ __launch_bounds__(512) void k_convm(const float* __restrict__ edc1d,
    const float* __restrict__ lk, const float* __restrict__ eg,
    const unsigned* __restrict__ parbits, const unsigned* __restrict__ cpref,
    float* __restrict__ rir)
{
    __shared__ float kerf[1024];
    __shared__ __align__(16) unsigned short afr[33 * 64 * 8];  // A frags [kb][lane][e]
    __shared__ __align__(16) unsigned short sbf[3136];         // swizzled bf16 window
    __shared__ float sf32[2049];
    int b = blockIdx.x, tb0 = blockIdx.y * 2048, tid = threadIdx.x;
    const float* src = edc1d + (long)b * TN;
    for (int k = tid; k < 1024; k += 512)
        kerf[k] = lk[k] + (k < 43 ? eg[k] : 0.f);
    for (int ch = tid; ch < 388; ch += 512) {
        unsigned short h[8];
        #pragma unroll
        for (int e = 0; e < 8; ++e) {
            int gt = tb0 + ch * 8 + e - 1031;
            float v = (gt >= 0 && gt <= OUT_LEN) ? src[gt] : 0.f;
            h[e] = f2bu(v);
        }
        int cs = ch ^ ((ch >> 3) & 7);
        *(uint4*)(&sbf[cs * 8]) = pack8(h);
    }
    for (int u = tid; u < 2049; u += 512) {
        int gt = tb0 + u;
        sf32[u] = (gt <= OUT_LEN) ? src[gt] : 0.f;
    }
    __syncthreads();
    for (int sl = tid; sl < 33 * 64; sl += 512) {
        int kb = sl >> 6, l = sl & 63;
        int x0 = kb * 32 - 1 + (l & 15) - 8 * (l >> 4);    // x = x0 - e
        unsigned short h[8];
        #pragma unroll
        for (int e = 0; e < 8; ++e) {
            int x = x0 - e;
            float v = (x >= 0 && x < 1024) ? kerf[x] : 0.f;
            h[e] = f2bu(v);
        }
        *(uint4*)(&afr[sl * 8]) = pack8(h);
    }
    __syncthreads();
    int lane = tid & 63, wv = tid >> 6;                    // 8 waves, 1 C-tile each
    int tb = tb0 + wv * 256;
    int cq = wv * 256 + 16 * (lane & 15) + 8 * (lane >> 4) + 1032;  // B chunk base (kb=0)
    f32x4 acc = {0.f, 0.f, 0.f, 0.f};
    for (int kb = 0; kb < 33; ++kb) {
        uint4 araw = *(const uint4*)(&afr[(kb * 64 + lane) * 8]);
        int ch = (cq - (kb << 5)) >> 3;
        int cs = ch ^ ((ch >> 3) & 7);
        uint4 braw = *(const uint4*)(&sbf[cs * 8]);
        acc = mfma16(araw, braw, acc);
    }
    int c = lane & 15, q = lane >> 4;
    int t4 = tb + 16 * c + 4 * q;
    if (t4 < OUT_LEN) {
        int u0 = t4 - tb0;
        unsigned pw = parbits[b * 1000 + (t4 >> 5)];       // 4 bits same word (t4%4==0)
        unsigned cp = cpref[(t4 >> 8) * 64 + b] & 1u;
        int sh = t4 & 31;
        float sv[5];
        #pragma unroll
        for (int e = 0; e < 5; ++e) sv[e] = sf32[u0 + e];
        float r[4];
        #pragma unroll
        for (int reg = 0; reg < 4; ++reg) {
            float diff = sv[reg] - sv[reg + 1];
            float amp = diff > 0.f ? sqrtf(diff) : 0.f;
            unsigned p = ((pw >> (sh + reg)) & 1u) ^ cp;
            r[reg] = acc[reg] * amp * (p ? -1.f : 1.f);
        }
        *(float4*)(rir + (long)b * OUT_LEN + t4) = make_float4(r[0], r[1], r[2], r[3]);
    }
}

extern "C" void kernel_launch(void* const* d_in, const int* in_sizes, int n_in,
                              void* d_out, int out_size, void* d_ws, size_t ws_size,
                              hipStream_t stream) {
    (void)in_sizes; (void)n_in; (void)out_size; (void)ws_size;
    const float* x    = (const float*)d_in[0];
    const float* lW1  = (const float*)d_in[1];  const float* lb1 = (const float*)d_in[2];
    const float* lW2  = (const float*)d_in[3];  const float* lb2 = (const float*)d_in[4];
    const float* eW1  = (const float*)d_in[5];  const float* eb1 = (const float*)d_in[6];
    const float* eW2  = (const float*)d_in[7];  const float* eb2 = (const float*)d_in[8];
    const float* dW1  = (const float*)d_in[9];  const float* db1 = (const float*)d_in[10];
    const float* dW2  = (const float*)d_in[11]; const float* db2 = (const float*)d_in[12];
    const float* aW1  = (const float*)d_in[13]; const float* ab1 = (const float*)d_in[14];
    const float* aW2  = (const float*)d_in[15]; const float* ab2 = (const float*)d_in[16];
    const float* bW1  = (const float*)d_in[17]; const float* bb1 = (const float*)d_in[18];
    const float* bW2  = (const float*)d_in[19]; const float* bb2 = (const float*)d_in[20];
    const float* eg   = (const float*)d_in[21]; const float* lkk = (const float*)d_in[22];
    const int* flips  = (const int*)d_in[23];

    float* out = (float*)d_out;                    // f32 output buffer
    float* rir = out;                              // 2,048,000
    float* edc = out + 2048000;                    // 16,384,512
    float* olk = out + 18432512;                   // 1,024
    float* oa  = out + 18433536;                   // 1,024
    float* ob  = out + 18434560;                   // 1,024

    // -------- ws layout (<= 10.6 MB, well under proven 18.65 MB) --------
    char* wsb = (char*)d_ws;
    float*    ws_h1   = (float*)(wsb + 1024);       // 16,384 B
    unsigned* ws_ct   = (unsigned*)(wsb + 18432);   // 32,000 B
    unsigned* ws_cp   = (unsigned*)(wsb + 50688);   // 32,000 B
    unsigned* ws_pb   = (unsigned*)(wsb + 82944);   // 256,000 B
    float*    ws_b2x  = (float*)(wsb + 339200);     // 96 B
    float*    ws_wbl  = (float*)(wsb + 345600);     // 6,144 B  (wbL: 1536 f32)
    float*    ws_e1d  = (float*)(wsb + 352256);     // 8,192,256 B -> ends 8,544,512
    float*    ws_wbp  = (float*)(wsb + 8544512);    // 1001*512*4 = 2,050,048 B -> 10,594,560

    k_h1<<<16, 256, 0, stream>>>(x, lW1, lb1, ws_h1);
    k_par1<<<dim3(64, 125), 256, 0, stream>>>(flips, ws_pb, ws_ct);
    k_par2<<<1, 64, 0, stream>>>(ws_ct, ws_cp);
    k_gemm<<<1001, 512, 0, stream>>>(lW2, lb2, ws_h1, edc, ws_e1d, ws_wbp);
    k_wbred<<<512, 64, 0, stream>>>(ws_wbp, ws_wbl);
    k_b2red<<<8, 256, 0, stream>>>(lb2, ws_b2x);
    k_mlp<<<64, 64, 0, stream>>>(x, ws_wbl, ws_b2x, ws_h1,
                                 eW1, eb1, eW2, eb2, dW1, db1, dW2, db2,
                                 aW1, ab1, aW2, ab2, bW1, bb1, bW2, bb2, olk, oa, ob);
    k_convm<<<dim3(64, 16), 512, 0, stream>>>(ws_e1d, lkk, eg, ws_pb, ws_cp, rir);
}

// Round 26
// 96.326 us; speedup vs baseline: 2.3612x; 1.4282x over previous
//
#include <hip/hip_runtime.h>
#include <hip/hip_bf16.h>

#define LJ 256008       // T*BANDS
#define TN 32001
#define OUT_LEN 32000

typedef __attribute__((ext_vector_type(8))) short short8v;
typedef __attribute__((ext_vector_type(8))) __bf16 bf16x8;
typedef __attribute__((ext_vector_type(4))) float f32x4;

__device__ __forceinline__ unsigned short f2bu(float f) {
    union { __hip_bfloat16 h; unsigned short u; } cv; cv.h = __float2bfloat16(f); return cv.u;
}
__device__ __forceinline__ uint4 pack8(const unsigned short* h) {
    return make_uint4((unsigned)h[0] | ((unsigned)h[1] << 16),
                      (unsigned)h[2] | ((unsigned)h[3] << 16),
                      (unsigned)h[4] | ((unsigned)h[5] << 16),
                      (unsigned)h[6] | ((unsigned)h[7] << 16));
}
__device__ __forceinline__ f32x4 mfma16(uint4 a, uint4 b, f32x4 c) {
    union { uint4 u; short8v s; bf16x8 v; } ua, ub;
    ua.u = a; ub.u = b;
    return __builtin_amdgcn_mfma_f32_16x16x32_bf16(ua.v, ub.v, c, 0, 0, 0);
}

// ---------------- h1 = relu(x @ lstm_W1 + b1), stored [i][b] (f32) ----------------
__global__ __launch_bounds__(256) void k_h1(const float* __restrict__ x,
                                            const float* __restrict__ W1,
                                            const float* __restrict__ b1,
                                            float* __restrict__ h1)
{
    int idx = blockIdx.x * 256 + threadIdx.x;   // 4096 outputs
    if (idx >= 4096) return;
    int b = idx >> 6, i = idx & 63;
    float acc = b1[i];
    #pragma unroll
    for (int f = 0; f < 16; ++f)
        acc += x[b * 16 + f] * W1[f * 64 + i];
    h1[i * 64 + b] = fmaxf(acc, 0.f);
}

// ---------------- conv A-fragments (kernel Toeplitz) precompute: block-invariant ---------------
__global__ __launch_bounds__(512) void k_aprep(const float* __restrict__ lk,
                                               const float* __restrict__ eg,
                                               uint4* __restrict__ afrg)
{
    __shared__ float kerf[1024];
    int tid = threadIdx.x;
    #pragma unroll
    for (int s = 0; s < 2; ++s) {
        int k = tid + 512 * s;
        kerf[k] = lk[k] + (k < 43 ? eg[k] : 0.f);
    }
    __syncthreads();
    for (int sl = tid; sl < 33 * 64; sl += 512) {
        int kb = sl >> 6, l = sl & 63;
        int x0 = kb * 32 - 1 + (l & 15) - 8 * (l >> 4);    // x = x0 - e
        unsigned short h[8];
        #pragma unroll
        for (int e = 0; e < 8; ++e) {
            int x = x0 - e;
            float v = (x >= 0 && x < 1024) ? kerf[x] : 0.f;
            h[e] = f2bu(v);
        }
        afrg[sl] = pack8(h);
    }
}

// ---- Fused MFMA GEMM (R20, measured 52us): edc + exact-f32 edc1d + P band partials ------------
__global__ __launch_bounds__(512) void k_gemm(const float* __restrict__ W2,
                                              const float* __restrict__ b2,
                                              const float* __restrict__ h1,
                                              float* __restrict__ edc,
                                              float* __restrict__ edc1d,
                                              float* __restrict__ P)
{
    __shared__ float h1T[64 * 68];                         // 17.4 KB: [b][i], pad 68
    __shared__ float w2f[8192];                            // 32 KB: [row(32)][col(256)] f32 chunk
    __shared__ __align__(16) unsigned short afr[4096];     // 8 KB: [bt(4)][kb(2)][lane][e]
    __shared__ float wbandT[32 * 68];                      // 8.7 KB: [tl][i], pad 68
    __shared__ float bband[32];
    int tid = threadIdx.x;
    long C0 = (long)blockIdx.x * 256;
    float4 z4 = make_float4(0.f, 0.f, 0.f, 0.f);

    // stage h1 transposed: [b][i]
    #pragma unroll
    for (int s = 0; s < 8; ++s) {
        int g = tid + 512 * s;
        float v = h1[g];
        h1T[(g & 63) * 68 + (g >> 6)] = v;
    }
    // stage A fragments (one slot per thread): bt=tid>>7, kb=(tid>>6)&1, l=tid&63
    {
        int bt = tid >> 7, kb = (tid >> 6) & 1, l = tid & 63;
        int q = l >> 4, r = l & 15;
        unsigned short hh[8];
        #pragma unroll
        for (int e = 0; e < 8; ++e)
            hh[e] = f2bu(h1[(32 * kb + 8 * q + e) * 64 + 16 * bt + r]);
        *(uint4*)(&afr[tid * 8]) = pack8(hh);
    }
    // b2 band-sums
    if (tid < 32) {
        long c8 = C0 + 8 * tid;
        float sum = 0.f;
        if (c8 + 7 < LJ) {
            float4 u0 = *(const float4*)(b2 + c8);
            float4 u1 = *(const float4*)(b2 + c8 + 4);
            sum = ((u0.x + u0.y) + (u0.z + u0.w)) + ((u1.x + u1.y) + (u1.z + u1.w));
        }
        bband[tid] = sum;
    }
    // stage w2f chunk kb=0 (rows 0..31), coalesced float4
    #pragma unroll
    for (int s = 0; s < 4; ++s) {
        int slot = tid + 512 * s;                      // 2048 float4 slots
        int row = slot >> 6, c4 = slot & 63;
        long col = C0 + 4 * c4;
        float4 v = (col < LJ) ? *(const float4*)(W2 + (long)row * LJ + col) : z4;
        *(float4*)(&w2f[row * 256 + 4 * c4]) = v;
    }
    __syncthreads();

    int lane = tid & 63, wv = tid >> 6;
    int q = lane >> 4, r = lane & 15;
    f32x4 acc[2][4];
    #pragma unroll
    for (int c = 0; c < 2; ++c)
        #pragma unroll
        for (int b = 0; b < 4; ++b) acc[c][b] = (f32x4){0.f, 0.f, 0.f, 0.f};

    // wbandT rows for i = 0..31 from LDS
    #pragma unroll
    for (int s = 0; s < 2; ++s) {
        int en = tid + 512 * s;                        // 1024 entries
        int i = en >> 5, tl = en & 31;
        const float* p = &w2f[i * 256 + 8 * tl];
        wbandT[tl * 68 + i] = ((p[0] + p[1]) + (p[2] + p[3])) + ((p[4] + p[5]) + (p[6] + p[7]));
    }
    // MFMA kb=0, B frags from LDS
    #pragma unroll
    for (int ctl = 0; ctl < 2; ++ctl) {
        int ct = wv * 2 + ctl;
        unsigned short hh[8];
        #pragma unroll
        for (int e = 0; e < 8; ++e)
            hh[e] = f2bu(w2f[(8 * q + e) * 256 + 16 * ct + r]);
        uint4 braw = pack8(hh);
        #pragma unroll
        for (int bt = 0; bt < 4; ++bt) {
            uint4 araw = *(const uint4*)(&afr[((bt * 2 + 0) * 64 + lane) * 8]);
            acc[ctl][bt] = mfma16(araw, braw, acc[ctl][bt]);
        }
    }
    __syncthreads();                                   // done reading w2f(kb0)
    // stage w2f chunk kb=1 (rows 32..63)
    #pragma unroll
    for (int s = 0; s < 4; ++s) {
        int slot = tid + 512 * s;
        int row = slot >> 6, c4 = slot & 63;
        long col = C0 + 4 * c4;
        float4 v = (col < LJ) ? *(const float4*)(W2 + (long)(32 + row) * LJ + col) : z4;
        *(float4*)(&w2f[row * 256 + 4 * c4]) = v;
    }
    __syncthreads();
    // wbandT rows for i = 32..63
    #pragma unroll
    for (int s = 0; s < 2; ++s) {
        int en = tid + 512 * s;
        int i2 = en >> 5, tl = en & 31;
        const float* p = &w2f[i2 * 256 + 8 * tl];
        wbandT[tl * 68 + 32 + i2] = ((p[0] + p[1]) + (p[2] + p[3])) + ((p[4] + p[5]) + (p[6] + p[7]));
    }
    // MFMA kb=1
    #pragma unroll
    for (int ctl = 0; ctl < 2; ++ctl) {
        int ct = wv * 2 + ctl;
        unsigned short hh[8];
        #pragma unroll
        for (int e = 0; e < 8; ++e)
            hh[e] = f2bu(w2f[(8 * q + e) * 256 + 16 * ct + r]);
        uint4 braw = pack8(hh);
        #pragma unroll
        for (int bt = 0; bt < 4; ++bt) {
            uint4 araw = *(const uint4*)(&afr[((bt * 2 + 1) * 64 + lane) * 8]);
            acc[ctl][bt] = mfma16(araw, braw, acc[ctl][bt]);
        }
    }
    __syncthreads();                                   // wbandT complete

    // exact-f32 edc1d, vectorized: thread owns column tl (const), batches b0+16s
    {
        int tl = tid & 31;
        int b0 = tid >> 5;                             // 0..15
        long c8 = C0 + 8 * tl;
        if (c8 + 7 < LJ) {
            float d0 = bband[tl], d1 = d0, d2 = d0, d3 = d0;
            #pragma unroll
            for (int i0 = 0; i0 < 64; i0 += 8) {
                float4 wA = *(const float4*)(&wbandT[tl * 68 + i0]);
                float4 wB = *(const float4*)(&wbandT[tl * 68 + i0 + 4]);
                {
                    float4 hA = *(const float4*)(&h1T[(b0 +  0) * 68 + i0]);
                    float4 hB = *(const float4*)(&h1T[(b0 +  0) * 68 + i0 + 4]);
                    d0 += hA.x*wA.x + hA.y*wA.y + hA.z*wA.z + hA.w*wA.w
                        + hB.x*wB.x + hB.y*wB.y + hB.z*wB.z + hB.w*wB.w;
                }
                {
                    float4 hA = *(const float4*)(&h1T[(b0 + 16) * 68 + i0]);
                    float4 hB = *(const float4*)(&h1T[(b0 + 16) * 68 + i0 + 4]);
                    d1 += hA.x*wA.x + hA.y*wA.y + hA.z*wA.z + hA.w*wA.w
                        + hB.x*wB.x + hB.y*wB.y + hB.z*wB.z + hB.w*wB.w;
                }
                {
                    float4 hA = *(const float4*)(&h1T[(b0 + 32) * 68 + i0]);
                    float4 hB = *(const float4*)(&h1T[(b0 + 32) * 68 + i0 + 4]);
                    d2 += hA.x*wA.x + hA.y*wA.y + hA.z*wA.z + hA.w*wA.w
                        + hB.x*wB.x + hB.y*wB.y + hB.z*wB.z + hB.w*wB.w;
                }
                {
                    float4 hA = *(const float4*)(&h1T[(b0 + 48) * 68 + i0]);
                    float4 hB = *(const float4*)(&h1T[(b0 + 48) * 68 + i0 + 4]);
                    d3 += hA.x*wA.x + hA.y*wA.y + hA.z*wA.z + hA.w*wA.w
                        + hB.x*wB.x + hB.y*wB.y + hB.z*wB.z + hB.w*wB.w;
                }
            }
            int tcol = (int)(C0 >> 3) + tl;
            edc1d[(long)(b0 +  0) * TN + tcol] = d0 * 0.125f;
            edc1d[(long)(b0 + 16) * TN + tcol] = d1 * 0.125f;
            edc1d[(long)(b0 + 32) * TN + tcol] = d2 * 0.125f;
            edc1d[(long)(b0 + 48) * TN + tcol] = d3 * 0.125f;
        }
    }

    // epilogue: edc stores + band partial sums
    float psum[4][4];
    #pragma unroll
    for (int bt = 0; bt < 4; ++bt)
        #pragma unroll
        for (int rg = 0; rg < 4; ++rg) psum[bt][rg] = 0.f;
    #pragma unroll
    for (int ctl = 0; ctl < 2; ++ctl) {
        int ct = wv * 2 + ctl;
        long col = C0 + 16 * ct + r;
        bool okc = col < LJ;
        float bias = okc ? b2[col] : 0.f;
        #pragma unroll
        for (int bt = 0; bt < 4; ++bt) {
            #pragma unroll
            for (int rg = 0; rg < 4; ++rg) {
                float v = acc[ctl][bt][rg] + bias;      // 0 for invalid cols (B staged 0)
                if (okc) edc[(long)(16 * bt + 4 * q + rg) * LJ + col] = v;
                float sps = v + __shfl_xor(v, 8);       // band-sum over {r, r^8}
                psum[bt][rg] += sps;
            }
        }
    }
    if (r < 8) {
        #pragma unroll
        for (int bt = 0; bt < 4; ++bt)
            #pragma unroll
            for (int rg = 0; rg < 4; ++rg)
                P[(long)blockIdx.x * 512 + (16 * bt + 4 * q + rg) * 8 + r] = psum[bt][rg];
    }
}

// ---------------- sum block partials -> sums[b][band][{all,q1,q4}] ----------------
__global__ __launch_bounds__(512) void k_redsum(const float* __restrict__ P,
                                                float* __restrict__ sums)
{
    int g = blockIdx.x, t = threadIdx.x;           // t = batch*8 + band
    int b = t >> 3, band = t & 7;
    int s0 = g * 16, s1 = s0 + 16;
    if (s1 > 1001) s1 = 1001;
    float all = 0.f, q1 = 0.f, q4 = 0.f;
    for (int blk = s0; blk < s1; ++blk) {
        float v = P[(long)blk * 512 + t];
        all += v;
        if (blk < 250) q1 += v;                    // t < 8000  <=> j < 64000
        if (blk >= 750) q4 += v;                   // t >= 24000 <=> j >= 192000
    }
    atomicAdd(&sums[b * 24 + band * 3 + 0], all);
    atomicAdd(&sums[b * 24 + band * 3 + 1], q1);
    atomicAdd(&sums[b * 24 + band * 3 + 2], q4);
}

// ---------------- small MLP head: one block per batch row, f32 outputs ----------------
__global__ __launch_bounds__(64) void k_mlp(const float* __restrict__ x,
    const float* __restrict__ sums,
    const float* __restrict__ eW1, const float* __restrict__ eb1,
    const float* __restrict__ eW2, const float* __restrict__ eb2,
    const float* __restrict__ dW1, const float* __restrict__ db1,
    const float* __restrict__ dW2, const float* __restrict__ db2,
    const float* __restrict__ aW1, const float* __restrict__ ab1,
    const float* __restrict__ aW2, const float* __restrict__ ab2,
    const float* __restrict__ bW1, const float* __restrict__ bb1,
    const float* __restrict__ bW2, const float* __restrict__ bb2,
    float* __restrict__ out_lk, float* __restrict__ out_a, float* __restrict__ out_b)
{
    int b = blockIdx.x, o = threadIdx.x;
    __shared__ float feat[16], a1[64], hh[64], t1[64];
    if (o < 16) {
        float v;
        if (o < 8) v = sums[b * 24 + o * 3] * (1.f / 32001.f);
        else {
            int band = o - 8;
            v = sums[b * 24 + band * 3 + 2] * (1.f / 8001.f)
              - sums[b * 24 + band * 3 + 1] * (1.f / 8000.f);
        }
        feat[o] = v;
    }
    __syncthreads();
    {   float acc = eb1[o];
        #pragma unroll
        for (int c = 0; c < 16; ++c) acc += feat[c] * eW1[c * 64 + o];
        a1[o] = fmaxf(acc, 0.f); }
    __syncthreads();
    {   float acc = eb2[o];
        for (int c = 0; c < 64; ++c) acc += a1[c] * eW2[c * 64 + o];
        hh[o] = fmaxf(acc, 0.f); }
    __syncthreads();
    {   float acc = db1[o];
        #pragma unroll
        for (int c = 0; c < 3; ++c) acc += x[b * 16 + c] * dW1[c * 64 + o];
        for (int c = 0; c < 64; ++c) acc += hh[c] * dW1[(3 + c) * 64 + o];
        t1[o] = fmaxf(acc, 0.f); }
    __syncthreads();
    if (o < 16) {
        float acc = db2[o];
        for (int c = 0; c < 64; ++c) acc += t1[c] * dW2[c * 16 + o];
        out_lk[b * 16 + o] = acc;
    }
    __syncthreads();
    if (o < 32) {
        float acc = ab1[o];
        for (int c = 0; c < 64; ++c) acc += hh[c] * aW1[c * 32 + o];
        t1[o] = fmaxf(acc, 0.f);
    }
    __syncthreads();
    if (o < 16) {
        float acc = ab2[o];
        for (int c = 0; c < 32; ++c) acc += t1[c] * aW2[c * 16 + o];
        out_a[b * 16 + o] = acc;
    }
    __syncthreads();
    if (o < 32) {
        float acc = bb1[o];
        for (int c = 0; c < 64; ++c) acc += hh[c] * bW1[c * 32 + o];
        t1[o] = fmaxf(acc, 0.f);
    }
    __syncthreads();
    if (o < 16) {
        float acc = bb2[o];
        for (int c = 0; c < 32; ++c) acc += t1[c] * bW2[c * 16 + o];
        out_b[b * 16 + o] = acc;
    }
}

// ---------------- parity stage 1: packed bits (per-(b, 256-chunk) inclusive XOR scan) ----------
__global__ __launch_bounds__(256) void k_par1(const int* __restrict__ flips,
                                              unsigned* __restrict__ parbits,
                                              unsigned* __restrict__ ctot)
{
    int b = blockIdx.x, c = blockIdx.y, tid = threadIdx.x;
    int t = c * 256 + tid;
    int bit = (t == 0) ? 0 : (flips[(long)b * OUT_LEN + t] & 1);
    int lane = tid & 63, wv = tid >> 6;
    unsigned long long mask = __ballot(bit != 0);
    int below = ((int)__popcll(mask & ((1ull << lane) - 1ull))) & 1;
    int incl = below ^ bit;
    __shared__ int wtot[4];
    if (lane == 0) wtot[wv] = ((int)__popcll(mask)) & 1;
    __syncthreads();
    int pre = 0;
    for (int w = 0; w < wv; ++w) pre ^= wtot[w];
    int inclB = pre ^ incl;
    unsigned long long m2 = __ballot(inclB != 0);
    if (lane == 0)  parbits[b * 1000 + c * 8 + wv * 2 + 0] = (unsigned)(m2 & 0xffffffffull);
    if (lane == 32) parbits[b * 1000 + c * 8 + wv * 2 + 1] = (unsigned)(m2 >> 32);
    if (tid == 0) ctot[c * 64 + b] = (unsigned)(wtot[0] ^ wtot[1] ^ wtot[2] ^ wtot[3]);
}

// ---------------- parity stage 2: exclusive prefix over chunks ----------------
__global__ __launch_bounds__(64) void k_par2(const unsigned* __restrict__ ctot,
                                             unsigned* __restrict__ cpref)
{
    int b = threadIdx.x;
    unsigned carry = 0;
    for (int c = 0; c < 125; ++c) {
        cpref[c * 64 + b] = carry;
        carry ^= ctot[c * 64 + b];
    }
}

// ------- MFMA Toeplitz conv: A-frags precomputed (L2-hot coalesced), sbf swizzled --------------
__global__ __launch_bounds__(512) void k_convm(const float* __restrict__ edc1d,
    const uint4* __restrict__ afrg,
    const unsigned* __restrict__ parbits, const unsigned* __restrict__ cpref,
    float* __restrict__ rir)
{
    __shared__ __align__(16) unsigned short sbf[3136];         // swizzled bf16 window
    __shared__ float sf32[2049];
    int b = blockIdx.x, tb0 = blockIdx.y * 2048, tid = threadIdx.x;
    const float* src = edc1d + (long)b * TN;
    for (int ch = tid; ch < 388; ch += 512) {
        unsigned short h[8];
        #pragma unroll
        for (int e = 0; e < 8; ++e) {
            int gt = tb0 + ch * 8 + e - 1031;
            float v = (gt >= 0 && gt <= OUT_LEN) ? src[gt] : 0.f;
            h[e] = f2bu(v);
        }
        int cs = ch ^ ((ch >> 3) & 7);
        *(uint4*)(&sbf[cs * 8]) = pack8(h);
    }
    for (int u = tid; u < 2049; u += 512) {
        int gt = tb0 + u;
        sf32[u] = (gt <= OUT_LEN) ? src[gt] : 0.f;
    }
    __syncthreads();
    int lane = tid & 63, wv = tid >> 6;                    // 8 waves, 1 C-tile each
    int tb = tb0 + wv * 256;
    int cq = wv * 256 + 16 * (lane & 15) + 8 * (lane >> 4) + 1032;  // B chunk base (kb=0)
    f32x4 acc = {0.f, 0.f, 0.f, 0.f};
    for (int kb = 0; kb < 33; ++kb) {
        uint4 araw = afrg[kb * 64 + lane];                 // coalesced, L2-hot, block-invariant
        int ch = (cq - (kb << 5)) >> 3;
        int cs = ch ^ ((ch >> 3) & 7);
        uint4 braw = *(const uint4*)(&sbf[cs * 8]);
        acc = mfma16(araw, braw, acc);
    }
    int c = lane & 15, q = lane >> 4;
    int t4 = tb + 16 * c + 4 * q;
    if (t4 < OUT_LEN) {
        int u0 = t4 - tb0;
        unsigned pw = parbits[b * 1000 + (t4 >> 5)];       // 4 bits same word (t4%4==0)
        unsigned cp = cpref[(t4 >> 8) * 64 + b] & 1u;
        int sh = t4 & 31;
        float sv[5];
        #pragma unroll
        for (int e = 0; e < 5; ++e) sv[e] = sf32[u0 + e];
        float r[4];
        #pragma unroll
        for (int reg = 0; reg < 4; ++reg) {
            float diff = sv[reg] - sv[reg + 1];
            float amp = diff > 0.f ? sqrtf(diff) : 0.f;
            unsigned p = ((pw >> (sh + reg)) & 1u) ^ cp;
            r[reg] = acc[reg] * amp * (p ? -1.f : 1.f);
        }
        *(float4*)(rir + (long)b * OUT_LEN + t4) = make_float4(r[0], r[1], r[2], r[3]);
    }
}

extern "C" void kernel_launch(void* const* d_in, const int* in_sizes, int n_in,
                              void* d_out, int out_size, void* d_ws, size_t ws_size,
                              hipStream_t stream) {
    (void)in_sizes; (void)n_in; (void)out_size; (void)ws_size;
    const float* x    = (const float*)d_in[0];
    const float* lW1  = (const float*)d_in[1];  const float* lb1 = (const float*)d_in[2];
    const float* lW2  = (const float*)d_in[3];  const float* lb2 = (const float*)d_in[4];
    const float* eW1  = (const float*)d_in[5];  const float* eb1 = (const float*)d_in[6];
    const float* eW2  = (const float*)d_in[7];  const float* eb2 = (const float*)d_in[8];
    const float* dW1  = (const float*)d_in[9];  const float* db1 = (const float*)d_in[10];
    const float* dW2  = (const float*)d_in[11]; const float* db2 = (const float*)d_in[12];
    const float* aW1  = (const float*)d_in[13]; const float* ab1 = (const float*)d_in[14];
    const float* aW2  = (const float*)d_in[15]; const float* ab2 = (const float*)d_in[16];
    const float* bW1  = (const float*)d_in[17]; const float* bb1 = (const float*)d_in[18];
    const float* bW2  = (const float*)d_in[19]; const float* bb2 = (const float*)d_in[20];
    const float* eg   = (const float*)d_in[21]; const float* lkk = (const float*)d_in[22];
    const int* flips  = (const int*)d_in[23];

    float* out = (float*)d_out;                    // f32 output buffer
    float* rir = out;                              // 2,048,000
    float* edc = out + 2048000;                    // 16,384,512
    float* olk = out + 18432512;                   // 1,024
    float* oa  = out + 18433536;                   // 1,024
    float* ob  = out + 18434560;                   // 1,024

    // -------- ws layout (<= 10.63 MB, well under proven 18.65 MB) --------
    char* wsb = (char*)d_ws;
    float*    ws_h1   = (float*)(wsb + 1024);       // 16,384 B
    unsigned* ws_ct   = (unsigned*)(wsb + 18432);   // 32,000 B
    unsigned* ws_cp   = (unsigned*)(wsb + 50688);   // 32,000 B
    unsigned* ws_pb   = (unsigned*)(wsb + 82944);   // 256,000 B
    float*    ws_sums = (float*)(wsb + 339200);     // 6,144 B
    float*    ws_e1d  = (float*)(wsb + 346112);     // 8,192,256 B -> ends 8,538,368
    float*    ws_part = (float*)(wsb + 8538368);    // 2,050,048 B -> ends 10,588,416
    uint4*    ws_cafr = (uint4*)(wsb + 10588416);   // 33*64*16 = 33,792 B

    hipMemsetAsync(ws_sums, 0, 64 * 24 * sizeof(float), stream);

    k_h1<<<16, 256, 0, stream>>>(x, lW1, lb1, ws_h1);
    k_aprep<<<1, 512, 0, stream>>>(lkk, eg, ws_cafr);
    k_par1<<<dim3(64, 125), 256, 0, stream>>>(flips, ws_pb, ws_ct);
    k_par2<<<1, 64, 0, stream>>>(ws_ct, ws_cp);
    k_gemm<<<1001, 512, 0, stream>>>(lW2, lb2, ws_h1, edc, ws_e1d, ws_part);
    k_redsum<<<63, 512, 0, stream>>>(ws_part, ws_sums);
    k_mlp<<<64, 64, 0, stream>>>(x, ws_sums, eW1, eb1, eW2, eb2, dW1, db1, dW2, db2,
                                 aW1, ab1, aW2, ab2, bW1, bb1, bW2, bb2, olk, oa, ob);
    k_convm<<<dim3(64, 16), 512, 0, stream>>>(ws_e1d, ws_cafr, ws_pb, ws_cp, rir);
}